// Round 14
// baseline (497.371 us; speedup 1.0000x reference)
//
#include <hip/hip_runtime.h>
#include <cstdint>
#include <cstddef>

typedef unsigned int uint;
typedef unsigned short ushort;

typedef __bf16 bf16x8 __attribute__((ext_vector_type(8)));
typedef float f32x4 __attribute__((ext_vector_type(4)));

// ---------- bf16 helpers (bit-level) ----------
__device__ __forceinline__ float bflo(uint u) { return __uint_as_float(u << 16); }
__device__ __forceinline__ float bfhi(uint u) { return __uint_as_float(u & 0xffff0000u); }
__device__ __forceinline__ float bf2f(ushort s) { return __uint_as_float(((uint)s) << 16); }
__device__ __forceinline__ ushort f2bf(float f) {
    uint u = __float_as_uint(f);
    u += 0x7fffu + ((u >> 16) & 1u);   // round-to-nearest-even
    return (ushort)(u >> 16);
}
__device__ __forceinline__ uint pk2(float lo, float hi) {
    return (uint)f2bf(lo) | ((uint)f2bf(hi) << 16);
}
__device__ __forceinline__ void unpack8(uint4 v, float* f) {
    f[0] = bflo(v.x); f[1] = bfhi(v.x); f[2] = bflo(v.y); f[3] = bfhi(v.y);
    f[4] = bflo(v.z); f[5] = bfhi(v.z); f[6] = bflo(v.w); f[7] = bfhi(v.w);
}

// async global->LDS, 16B per lane, wave-uniform LDS base (linear dest)
typedef __attribute__((address_space(1))) const unsigned int* as1_cuptr;
typedef __attribute__((address_space(3))) unsigned int* as3_uptr;
__device__ __forceinline__ void gload_lds16(const void* g, void* l) {
    __builtin_amdgcn_global_load_lds((as1_cuptr)g, (as3_uptr)l, 16, 0, 0);
}

// ---------- constants ----------
#define LTOT 4096           // b*l tokens (2 batches x 2048)
#define DMODEL 2048
#define DINNER 4096
#define DSTATE 128
#define NHEADS 64
#define CONVDIM 6144
#define DPROJ 10304
#define CHUNK 256
#define NCHUNK 16           // GLOBAL chunks (8 per batch x 2 batches)

// ============================================================
// fused fp32 -> bf16 conversion for u, W_in, W_out (one launch)
// ============================================================
__global__ void cvt_all(const float* __restrict__ u, const float* __restrict__ Wi,
                        const float* __restrict__ Wo, ushort* __restrict__ ub,
                        ushort* __restrict__ wib, ushort* __restrict__ wob) {
    int i = blockIdx.x * 256 + threadIdx.x;   // float4 index
    const float* src; ushort* dst; int j;
    if (i < 2097152)      { src = u;  dst = ub;  j = i; }
    else if (i < 7372800) { src = Wi; dst = wib; j = i - 2097152; }
    else if (i < 9469952) { src = Wo; dst = wob; j = i - 7372800; }
    else return;
    float4 v = ((const float4*)src)[j];
    ushort4 o;
    o.x = f2bf(v.x); o.y = f2bf(v.y); o.z = f2bf(v.z); o.w = f2bf(v.w);
    ((ushort4*)dst)[j] = o;
}

#define MFMA_OP __builtin_amdgcn_mfma_f32_16x16x32_bf16
#define RD8(BASE, OFF) (*(const bf16x8*)((BASE) + (OFF)))
#define MM8(M0, AV, BV) do { \
  _Pragma("unroll") \
  for (int _m = 0; _m < 2; _m++) \
    _Pragma("unroll") \
    for (int _n = 0; _n < 4; _n++) \
      acc[(M0)+_m][_n] = MFMA_OP(AV[(M0)+_m], BV[_n], acc[(M0)+_m][_n], 0, 0, 0); \
} while (0)

// ============================================================
// in_proj: 128x256-tile pipelined GEMM with pre-read (round-13
// out_proj schedule, A/B geometry swapped + scatter epilogue).
// A = X panel 128 rows (8KB/kh, 1 load/thread); B = W panel 256 rows
// (16KB/kh, 2 loads/thread). LDS 96 KiB -> grid 32x41=1312 blocks
// (5.125 rounds, tail 2.4% vs 15% at 256^2).
// kh0 phase: NO barrier - MFMA(16) on pre-read regs; stage kh0(t+1) [3].
// kh1 phase: vmcnt(3)+bar; read kh1 frags; stage kh1(t+1) [3];
//   MM8 m0-1; vmcnt(3)+bar; pre-read next-tile kh0; MM8 m2-3.
// vmcnt ages (per-thread, 3 loads/stage-pair): entries see 6
// outstanding, retire exactly the needed oldest 3. Same swizzle
// involution z = y ^ (((y>>7)&7)<<4) both sides (0 conflicts, r9-13).
// ============================================================
__global__ __launch_bounds__(512, 2) void gemm_in(
    const ushort* __restrict__ X, const ushort* __restrict__ W,
    ushort* __restrict__ zbuf, ushort* __restrict__ xbc, float* __restrict__ dtraw) {
    __shared__ ushort AL[2][8192];    // [buf][2 kh x 8KB]  = 32 KiB
    __shared__ ushort BL[2][16384];   // [buf][2 kh x 16KB] = 64 KiB
    const int NBN = 41;
    int q = gridDim.x >> 3;                 // 164
    int wg = blockIdx.x;
    int swz = (wg & 7) * q + (wg >> 3);
    int per = NBN * 4;                      // 164
    int sg = swz / per, rr = swz % per;     // sg = XCD id
    int bm = sg * 4 + (rr & 3);             // 0..31
    int bn = rr >> 2;                       // 0..40
    int tid = threadIdx.x;
    int lane = tid & 63, w = tid >> 6;
    int wr = w >> 2, wc = w & 3;            // 2 x 4 waves, wave out 64x64
    int lr = lane & 15, g = lane >> 4;
    int y00 = ((lr >> 1) << 7) | ((lr & 1) << 6) | (g << 4);
    int z00 = y00 ^ (((y00 >> 7) & 7) << 4);
    int aBase = wr * 4096 + z00;            // + kh*8192  + mf*1024 (mf<4)
    int bBase = wc * 4096 + z00;            // + kh*16384 + nf*1024 (nf<4)
    // staging decode (same involution). A: 1 slice; B: 2 slices.
    int z0 = tid * 16, z1 = z0 + 8192;
    int y0 = z0 ^ (((z0 >> 7) & 7) << 4);
    int y1 = z1 ^ (((z1 >> 7) & 7) << 4);
    int row0s = ((y0 >> 7) << 1) | ((y0 >> 6) & 1), kbe0 = (y0 & 63) >> 1;
    int row1s = ((y1 >> 7) << 1) | ((y1 >> 6) & 1), kbe1 = (y1 & 63) >> 1;
    const ushort* gA  = &X[(size_t)(bm * 128 + row0s) * 2048 + kbe0];   // rows 0..127
    const ushort* gB0 = &W[(size_t)(bn * 256 + row0s) * 2048 + kbe0];
    const ushort* gB1 = &W[(size_t)(bn * 256 + row1s) * 2048 + kbe1];
    int wOff = w * 1024;

#define STAGEA(DB, KP, KO) \
    gload_lds16(gA + (KO) + (KP) * 32, (char*)AL + (DB) * 16384 + (KP) * 8192 + wOff)
#define STAGEB(DB, KP, KO) do { \
    gload_lds16(gB0 + (KO) + (KP) * 32, (char*)BL + (DB) * 32768 + (KP) * 16384 + wOff); \
    gload_lds16(gB1 + (KO) + (KP) * 32, (char*)BL + (DB) * 32768 + (KP) * 16384 + wOff + 8192); \
} while (0)

    f32x4 acc[4][4] = {};
    bf16x8 aP[4], bP[4], aQ[4], bQ[4];
    // prologue: tile 0 (issue order: Akh0[1], Bkh0[2], Akh1[1], Bkh1[2])
    STAGEA(0, 0, 0); STAGEB(0, 0, 0);
    STAGEA(0, 1, 0); STAGEB(0, 1, 0);
    asm volatile("s_waitcnt vmcnt(3)" ::: "memory");   // kh0(0) done
    __builtin_amdgcn_s_barrier();
    __builtin_amdgcn_sched_barrier(0);
    #pragma unroll
    for (int i = 0; i < 4; i++) {
        bP[i] = RD8((const char*)BL, bBase + i * 1024);
        aP[i] = RD8((const char*)AL, aBase + i * 1024);
    }

    for (int t = 0; t < 32; ++t) {
        int buf = t & 1, nb = buf ^ 1;
        int ko = ((t + 1) & 31) * 64;       // tail: dummy re-stage of tile 0
        const char* Ab  = (const char*)AL + buf * 16384;
        const char* Bb  = (const char*)BL + buf * 32768;
        const char* AbN = (const char*)AL + nb * 16384;
        const char* BbN = (const char*)BL + nb * 32768;
        // ---- phase kh0: no barrier; MFMA on pre-read regs; stage kh0(t+1) ----
        STAGEA(nb, 0, ko); STAGEB(nb, 0, ko);
        __builtin_amdgcn_s_setprio(1);
        MM8(0, aP, bP);
        MM8(2, aP, bP);
        __builtin_amdgcn_s_setprio(0);
        __builtin_amdgcn_sched_barrier(0);
        // ---- phase kh1 ----
        asm volatile("s_waitcnt vmcnt(3)" ::: "memory");   // retires kh1(t)
        __builtin_amdgcn_s_barrier();
        __builtin_amdgcn_sched_barrier(0);
        #pragma unroll
        for (int i = 0; i < 4; i++) {
            bQ[i] = RD8(Bb, bBase + 16384 + i * 1024);
            aQ[i] = RD8(Ab, aBase + 8192 + i * 1024);
        }
        STAGEA(nb, 1, ko); STAGEB(nb, 1, ko);
        __builtin_amdgcn_s_setprio(1);
        MM8(0, aQ, bQ);
        __builtin_amdgcn_s_setprio(0);
        __builtin_amdgcn_sched_barrier(0);
        asm volatile("s_waitcnt vmcnt(3)" ::: "memory");   // retires kh0(t+1)
        __builtin_amdgcn_s_barrier();
        __builtin_amdgcn_sched_barrier(0);
        #pragma unroll
        for (int i = 0; i < 4; i++) {
            bP[i] = RD8(BbN, bBase + i * 1024);
            aP[i] = RD8(AbN, aBase + i * 1024);
        }
        __builtin_amdgcn_s_setprio(1);
        MM8(2, aQ, bQ);
        __builtin_amdgcn_s_setprio(0);
        __builtin_amdgcn_sched_barrier(0);
    }
    asm volatile("s_waitcnt vmcnt(0)" ::: "memory");

    // ---- scatter epilogue ----
    int rq = g * 4;
    #pragma unroll
    for (int mf = 0; mf < 4; mf++) {
        int row0 = bm * 128 + wr * 64 + mf * 16 + rq;
        #pragma unroll
        for (int nf = 0; nf < 4; nf++) {
            int cb0 = bn * 256 + wc * 64 + nf * 16;   // uniform; %16==0
            int col = cb0 + lr;
            if (cb0 < 4096) {
                #pragma unroll
                for (int r = 0; r < 4; r++)
                    zbuf[(size_t)(row0 + r) * DINNER + col] = f2bf(acc[mf][nf][r]);
            } else if (cb0 < 10240) {
                #pragma unroll
                for (int r = 0; r < 4; r++)
                    xbc[(size_t)(row0 + r) * CONVDIM + (col - 4096)] = f2bf(acc[mf][nf][r]);
            } else if (cb0 < 10304) {
                #pragma unroll
                for (int r = 0; r < 4; r++)
                    dtraw[(size_t)(row0 + r) * 64 + (col - 10240)] = acc[mf][nf][r];
            }
        }
    }
}
#undef STAGEA
#undef STAGEB

// ============================================================
// out_proj: 256x128-tile pipelined GEMM with pre-read (round 13, verified)
// ============================================================
__global__ __launch_bounds__(512, 2) void gemm256_out(
    const ushort* __restrict__ X, const ushort* __restrict__ W,
    float* __restrict__ outF) {
    __shared__ ushort AL[2][16384];   // 2 bufs x 32768 B (2 kh panels x 16 KB)
    __shared__ ushort BL[2][8192];    // 2 bufs x 16384 B (2 kh panels x 8 KB)
    int q = gridDim.x >> 3;                 // 32
    int wg = blockIdx.x;
    int swz = (wg & 7) * q + (wg >> 3);
    int per = 16 * 4;
    int sg = swz / per, rr = swz % per;
    int bm = sg * 4 + (rr & 3);
    int bn = rr >> 2;
    int tid = threadIdx.x;
    int lane = tid & 63, w = tid >> 6;
    int wr = w >> 1, wc = w & 1;
    int lr = lane & 15, g = lane >> 4;
    int y00 = ((lr >> 1) << 7) | ((lr & 1) << 6) | (g << 4);
    int z00 = y00 ^ (((y00 >> 7) & 7) << 4);
    int aBase = wr * 4096 + z00;
    int bBase = wc * 4096 + z00;
    int z0 = tid * 16, z1 = z0 + 8192;
    int y0 = z0 ^ (((z0 >> 7) & 7) << 4);
    int y1 = z1 ^ (((z1 >> 7) & 7) << 4);
    int rowA0 = ((y0 >> 7) << 1) | ((y0 >> 6) & 1), kA0 = (y0 & 63) >> 1;
    int rowA1 = ((y1 >> 7) << 1) | ((y1 >> 6) & 1), kA1 = (y1 & 63) >> 1;
    const ushort* gA0 = &X[(size_t)(bm * 256 + rowA0) * 4096 + kA0];
    const ushort* gA1 = &X[(size_t)(bm * 256 + rowA1) * 4096 + kA1];
    const ushort* gB  = &W[(size_t)(bn * 128 + rowA0) * 4096 + kA0];
    int wOff = w * 1024;

#define STAGEA(DB, KP, KO) do { \
    gload_lds16(gA0 + (KO) + (KP) * 32, (char*)AL + (DB) * 32768 + (KP) * 16384 + wOff); \
    gload_lds16(gA1 + (KO) + (KP) * 32, (char*)AL + (DB) * 32768 + (KP) * 16384 + wOff + 8192); \
} while (0)
#define STAGEB(DB, KP, KO) \
    gload_lds16(gB + (KO) + (KP) * 32, (char*)BL + (DB) * 16384 + (KP) * 8192 + wOff)

    f32x4 acc[4][4] = {};
    bf16x8 aP[4], bP[4], aQ[4], bQ[4];
    STAGEA(0, 0, 0); STAGEB(0, 0, 0);
    STAGEA(0, 1, 0); STAGEB(0, 1, 0);
    asm volatile("s_waitcnt vmcnt(3)" ::: "memory");
    __builtin_amdgcn_s_barrier();
    __builtin_amdgcn_sched_barrier(0);
    #pragma unroll
    for (int i = 0; i < 4; i++) {
        bP[i] = RD8((const char*)BL, bBase + i * 1024);
        aP[i] = RD8((const char*)AL, aBase + i * 1024);
    }

    for (int t = 0; t < 64; ++t) {
        int buf = t & 1, nb = buf ^ 1;
        int ko = ((t + 1) & 63) * 64;
        const char* Ab  = (const char*)AL + buf * 32768;
        const char* Bb  = (const char*)BL + buf * 16384;
        const char* AbN = (const char*)AL + nb * 32768;
        const char* BbN = (const char*)BL + nb * 16384;
        STAGEA(nb, 0, ko); STAGEB(nb, 0, ko);
        __builtin_amdgcn_s_setprio(1);
        MM8(0, aP, bP);
        MM8(2, aP, bP);
        __builtin_amdgcn_s_setprio(0);
        __builtin_amdgcn_sched_barrier(0);
        asm volatile("s_waitcnt vmcnt(3)" ::: "memory");
        __builtin_amdgcn_s_barrier();
        __builtin_amdgcn_sched_barrier(0);
        #pragma unroll
        for (int i = 0; i < 4; i++) {
            bQ[i] = RD8(Bb, bBase + 8192 + i * 1024);
            aQ[i] = RD8(Ab, aBase + 16384 + i * 1024);
        }
        STAGEA(nb, 1, ko); STAGEB(nb, 1, ko);
        __builtin_amdgcn_s_setprio(1);
        MM8(0, aQ, bQ);
        __builtin_amdgcn_s_setprio(0);
        __builtin_amdgcn_sched_barrier(0);
        asm volatile("s_waitcnt vmcnt(3)" ::: "memory");
        __builtin_amdgcn_s_barrier();
        __builtin_amdgcn_sched_barrier(0);
        #pragma unroll
        for (int i = 0; i < 4; i++) {
            bP[i] = RD8(BbN, bBase + i * 1024);
            aP[i] = RD8(AbN, aBase + i * 1024);
        }
        __builtin_amdgcn_s_setprio(1);
        MM8(2, aQ, bQ);
        __builtin_amdgcn_s_setprio(0);
        __builtin_amdgcn_sched_barrier(0);
    }
    asm volatile("s_waitcnt vmcnt(0)" ::: "memory");

    int rq = g * 4;
    #pragma unroll
    for (int mf = 0; mf < 4; mf++) {
        int row0 = bm * 256 + wr * 64 + mf * 16 + rq;
        #pragma unroll
        for (int nf = 0; nf < 4; nf++) {
            int col = bn * 128 + wc * 64 + nf * 16 + lr;
            #pragma unroll
            for (int r = 0; r < 4; r++)
                outF[(size_t)(row0 + r) * DMODEL + col] = acc[mf][nf][r];
        }
    }
}
#undef STAGEA
#undef STAGEB

// ============================================================
// causal depthwise conv1d (K=4) + SiLU: 4 rows x 8 ch per thread
// ============================================================
__global__ void conv_kernel(const ushort* __restrict__ xbc, const float* __restrict__ cw,
                            const float* __restrict__ cb, ushort* __restrict__ convout) {
    int c8 = (blockIdx.x * 256 + threadIdx.x) * 8;
    int row0 = blockIdx.y * 4;
    int t0 = row0 & 2047;
    float bias[8];
    {
        float4 b0 = ((const float4*)cb)[c8 / 4];
        float4 b1 = ((const float4*)cb)[c8 / 4 + 1];
        bias[0] = b0.x; bias[1] = b0.y; bias[2] = b0.z; bias[3] = b0.w;
        bias[4] = b1.x; bias[5] = b1.y; bias[6] = b1.z; bias[7] = b1.w;
    }
    float wk[8][4];
    #pragma unroll
    for (int e = 0; e < 8; e++) {
        float4 wv = ((const float4*)cw)[c8 + e];
        wk[e][0] = wv.x; wk[e][1] = wv.y; wk[e][2] = wv.z; wk[e][3] = wv.w;
    }
    float f[7][8];
    #pragma unroll
    for (int j = 0; j < 7; j++) {
        int tt = t0 - 3 + j;
        if (tt >= 0) {
            uint4 v = *(const uint4*)&xbc[(size_t)(row0 - 3 + j) * CONVDIM + c8];
            unpack8(v, f[j]);
        } else {
            #pragma unroll
            for (int e = 0; e < 8; e++) f[j][e] = 0.f;
        }
    }
    #pragma unroll
    for (int r = 0; r < 4; r++) {
        float a[8];
        #pragma unroll
        for (int e = 0; e < 8; e++) {
            a[e] = bias[e];
            #pragma unroll
            for (int k = 0; k < 4; k++) a[e] += f[r + k][e] * wk[e][k];
        }
        uint4 o;
        float s[8];
        #pragma unroll
        for (int e = 0; e < 8; e++) s[e] = a[e] / (1.f + __expf(-a[e]));
        o.x = pk2(s[0], s[1]); o.y = pk2(s[2], s[3]);
        o.z = pk2(s[4], s[5]); o.w = pk2(s[6], s[7]);
        *(uint4*)&convout[(size_t)(row0 + r) * CONVDIM + c8] = o;
    }
}

// ============================================================
// fused: softplus(dtraw+bias) (in place) + per-chunk cumsum of dt*A
// ============================================================
__global__ void cumsum_kernel(float* __restrict__ dtbuf, const float* __restrict__ dt_bias,
                              const float* __restrict__ A_log, float* __restrict__ dAcs) {
    int bi = blockIdx.x;
    int h = bi & 63, cg = bi >> 6;
    int t = threadIdx.x;
    size_t didx = (size_t)(cg * 256 + t) * 64 + h;
    float x = dtbuf[didx] + dt_bias[h];
    float sp = (x > 20.f) ? x : log1pf(__expf(x));
    dtbuf[didx] = sp;
    float A = -expf(A_log[h]);
    float v = sp * A;
    __shared__ float s[256];
    s[t] = v;
    __syncthreads();
    for (int off = 1; off < 256; off <<= 1) {
        float add = (t >= off) ? s[t - off] : 0.f;
        __syncthreads();
        s[t] += add;
        __syncthreads();
    }
    dAcs[(size_t)bi * 256 + t] = s[t];
}

// ============================================================
// MFMA states: per (cg,h), states[p][n] = sum_s xdt'[s,p] * B[s,n]
// ============================================================
__global__ __launch_bounds__(256) void states_mfma(
    const ushort* __restrict__ convout, const float* __restrict__ dtsp,
    const float* __restrict__ dAcs, float* __restrict__ states) {
    __shared__ ushort BT[128 * 72];
    __shared__ ushort XT[64 * 72];
    int bi = blockIdx.x;
    int h = bi & 63, cg = bi >> 6;
    int tid = threadIdx.x;
    int rowbase = cg * 256;
    int bcol = 1024 + ((h >> 3) << 7);
    int xcol = ((h >> 3) << 7) + ((h & 1) << 6);
    float dAlast = dAcs[(size_t)bi * 256 + 255];
    int w = tid >> 6, lane = tid & 63, g = lane >> 4, cc = lane & 15;
    f32x4 acc[4][2] = {};
    for (int T = 0; T < 4; T++) {
        __syncthreads();
        int s = lane;
        int srow = rowbase + T * 64 + s;
        #pragma unroll
        for (int i = 0; i < 4; i++) {
            int n0 = (w + i * 4) * 8;
            uint4 v = *(const uint4*)&convout[(size_t)srow * CONVDIM + bcol + n0];
            ushort us[8];
            us[0] = (ushort)v.x; us[1] = (ushort)(v.x >> 16);
            us[2] = (ushort)v.y; us[3] = (ushort)(v.y >> 16);
            us[4] = (ushort)v.z; us[5] = (ushort)(v.z >> 16);
            us[6] = (ushort)v.w; us[7] = (ushort)(v.w >> 16);
            #pragma unroll
            for (int e = 0; e < 8; e++) BT[(n0 + e) * 72 + s] = us[e];
        }
        float wgt = dtsp[(size_t)srow * 64 + h] * __expf(dAlast - dAcs[(size_t)bi * 256 + T * 64 + s]);
        #pragma unroll
        for (int j = 0; j < 2; j++) {
            int p0 = (w * 2 + j) * 8;
            uint4 v = *(const uint4*)&convout[(size_t)srow * CONVDIM + xcol + p0];
            float f[8]; unpack8(v, f);
            #pragma unroll
            for (int e = 0; e < 8; e++) XT[(p0 + e) * 72 + s] = f2bf(f[e] * wgt);
        }
        __syncthreads();
        bf16x8 af[4][2], bw[2][2];
        #pragma unroll
        for (int m = 0; m < 4; m++)
            #pragma unroll
            for (int kb = 0; kb < 2; kb++)
                af[m][kb] = *(const bf16x8*)&XT[(m * 16 + cc) * 72 + kb * 32 + 8 * g];
        #pragma unroll
        for (int np = 0; np < 2; np++)
            #pragma unroll
            for (int kb = 0; kb < 2; kb++)
                bw[np][kb] = *(const bf16x8*)&BT[(w * 32 + np * 16 + cc) * 72 + kb * 32 + 8 * g];
        #pragma unroll
        for (int m = 0; m < 4; m++)
            #pragma unroll
            for (int np = 0; np < 2; np++) {
                acc[m][np] = MFMA_OP(af[m][0], bw[np][0], acc[m][np], 0, 0, 0);
                acc[m][np] = MFMA_OP(af[m][1], bw[np][1], acc[m][np], 0, 0, 0);
            }
    }
    size_t base = (size_t)bi * 8192;
    #pragma unroll
    for (int m = 0; m < 4; m++)
        #pragma unroll
        for (int np = 0; np < 2; np++)
            #pragma unroll
            for (int r = 0; r < 4; r++) {
                int p = m * 16 + 4 * g + r;
                int n = w * 32 + np * 16 + cc;
                states[base + (size_t)p * 128 + n] = acc[m][np][r];
            }
}

// ============================================================
// inter-chunk recurrence: 8 chunks PER BATCH, carry resets per batch
// ============================================================
__global__ void recur_kernel(const float* __restrict__ dAcs, float* __restrict__ states) {
    int blk = blockIdx.x;
    int pq = blk & 7, bh = blk >> 3;
    int h = bh & 63, b = bh >> 6;
    int tid = threadIdx.x;
    int p = pq * 8 + (tid >> 5);
    int n0 = (tid & 31) * 4;
    float4 carry = make_float4(0.f, 0.f, 0.f, 0.f);
    for (int c = 0; c < 8; c++) {
        int bi = (b * 8 + c) * 64 + h;
        float decay = __expf(dAcs[(size_t)bi * 256 + 255]);
        size_t idx = (size_t)bi * 8192 + (size_t)p * 128 + n0;
        float4 tmp = *(const float4*)&states[idx];
        *(float4*)&states[idx] = carry;
        carry.x = carry.x * decay + tmp.x;
        carry.y = carry.y * decay + tmp.y;
        carry.z = carry.z * decay + tmp.z;
        carry.w = carry.w * decay + tmp.w;
    }
}

// ============================================================
// MFMA yscan: per (cg,h) block, Y = Y_diag + Y_off (D*x added in norm).
// ============================================================
__global__ __launch_bounds__(256, 2) void yscan_mfma(
    const ushort* __restrict__ convout, const float* __restrict__ dtsp,
    const float* __restrict__ dAcs, const float* __restrict__ states,
    ushort* __restrict__ y) {
    __shared__ ushort XT[64 * 264];
    __shared__ ushort PR[64 * 136];
    __shared__ ushort PV[4 * 16 * 72];
    __shared__ float sdA[256];
    int bi = blockIdx.x;
    int h = bi & 63, cg = bi >> 6;
    int tid = threadIdx.x;
    int rowbase = cg * 256;
    int bcol = 1024 + ((h >> 3) << 7);
    int ccol = 2048 + ((h >> 1) << 7);
    int xcol = ((h >> 3) << 7) + ((h & 1) << 6);

    sdA[tid] = dAcs[(size_t)bi * 256 + tid];
    #pragma unroll
    for (int i = 0; i < 4; i++) {
        int s = i * 64 + (tid & 63);
        float dtv = dtsp[(size_t)(rowbase + s) * 64 + h];
        #pragma unroll
        for (int j = 0; j < 2; j++) {
            int p0 = (((tid >> 6) << 1) + j) << 3;
            uint4 v = *(const uint4*)&convout[(size_t)(rowbase + s) * CONVDIM + xcol + p0];
            float f[8]; unpack8(v, f);
            #pragma unroll
            for (int e = 0; e < 8; e++) XT[(p0 + e) * 264 + s] = f2bf(f[e] * dtv);
        }
    }
    {
        const float* pv = &states[(size_t)bi * 8192];
        #pragma unroll
        for (int i = 0; i < 8; i++) {
            int flat = i * 1024 + tid * 4;
            float4 v = *(const float4*)&pv[flat];
            int p = flat >> 7, n = flat & 127;
            *(uint*)&PR[p * 136 + n]     = pk2(v.x, v.y);
            *(uint*)&PR[p * 136 + n + 2] = pk2(v.z, v.w);
        }
    }
    __syncthreads();

    int w = tid >> 6, lane = tid & 63, g = lane >> 4, c = lane & 15;
    int wbase = w * 64;
    const ushort* Crow0 = &convout[(size_t)(rowbase + wbase + c) * CONVDIM + ccol + 8 * g];

    // ---- Y_off = C . prev^T ----
    f32x4 yac[4][4] = {};
    #pragma unroll
    for (int kb = 0; kb < 4; kb++) {
        bf16x8 pb[4];
        #pragma unroll
        for (int np = 0; np < 4; np++)
            pb[np] = *(const bf16x8*)&PR[(16 * np + c) * 136 + kb * 32 + 8 * g];
        #pragma unroll
        for (int m = 0; m < 4; m++) {
            bf16x8 cf = *(const bf16x8*)&Crow0[(size_t)(m * 16) * CONVDIM + kb * 32];
            #pragma unroll
            for (int np = 0; np < 4; np++)
                yac[m][np] = MFMA_OP(cf, pb[np], yac[m][np], 0, 0, 0);
        }
    }
    float al[4][4];
    float Sw = sdA[wbase];
    float eSw = __expf(Sw);
    #pragma unroll
    for (int m = 0; m < 4; m++)
        #pragma unroll
        for (int r = 0; r < 4; r++) {
            float dAl = sdA[wbase + m * 16 + 4 * g + r];
            al[m][r] = __expf(dAl - Sw);
            float el = al[m][r] * eSw;
            #pragma unroll
            for (int np = 0; np < 4; np++) yac[m][np][r] *= el;
        }

    // ---- s-tiles ----
    ushort* pvs = &PV[w * 1152];
    for (int T = 0; T <= w; T++) {
        f32x4 sac[4][4] = {};
        #pragma unroll
        for (int kb = 0; kb < 4; kb++) {
            bf16x8 bb[4];
            #pragma unroll
            for (int np = 0; np < 4; np++)
                bb[np] = *(const bf16x8*)&convout[(size_t)(rowbase + T * 64 + 16 * np + c) * CONVDIM + bcol + kb * 32 + 8 * g];
            #pragma unroll
            for (int m = 0; m < 4; m++) {
                bf16x8 cf = *(const bf16x8*)&Crow0[(size_t)(m * 16) * CONVDIM + kb * 32];
                #pragma unroll
                for (int np = 0; np < 4; np++)
                    sac[m][np] = MFMA_OP(cf, bb[np], sac[m][np], 0, 0, 0);
            }
        }
        bf16x8 xb[4][2];
        #pragma unroll
        for (int np = 0; np < 4; np++)
            #pragma unroll
            for (int k2 = 0; k2 < 2; k2++)
                xb[np][k2] = *(const bf16x8*)&XT[(16 * np + c) * 264 + T * 64 + k2 * 32 + 8 * g];
        if (T < w) {
            float ET = sdA[T * 64 + 63];
            float cT = __expf(Sw - ET);
            float bc[4];
            #pragma unroll
            for (int np = 0; np < 4; np++)
                bc[np] = __expf(ET - sdA[T * 64 + 16 * np + c]) * cT;
            #pragma unroll
            for (int m = 0; m < 4; m++) {
                #pragma unroll
                for (int np = 0; np < 4; np++) {
                    float s0 = bc[np];
                    #pragma unroll
                    for (int r = 0; r < 4; r++)
                        pvs[(4 * g + r) * 72 + 16 * np + c] = f2bf(sac[m][np][r] * (al[m][r] * s0));
                }
                bf16x8 pa0 = *(const bf16x8*)&pvs[c * 72 + 8 * g];
                bf16x8 pa1 = *(const bf16x8*)&pvs[c * 72 + 32 + 8 * g];
                #pragma unroll
                for (int np = 0; np < 4; np++) {
                    yac[m][np] = MFMA_OP(pa0, xb[np][0], yac[m][np], 0, 0, 0);
                    yac[m][np] = MFMA_OP(pa1, xb[np][1], yac[m][np], 0, 0, 0);
                }
            }
        } else {
            #pragma unroll
            for (int m = 0; m < 4; m++) {
                float dal[4];
                #pragma unroll
                for (int r = 0; r < 4; r++) dal[r] = sdA[wbase + m * 16 + 4 * g + r];
                #pragma unroll
                for (int np = 0; np < 4; np++) {
                    int s_loc = w * 64 + 16 * np + c;
                    float dAs = sdA[s_loc];
                    #pragma unroll
                    for (int r = 0; r < 4; r++) {
                        int l_loc = wbase + m * 16 + 4 * g + r;
                        float v = (s_loc <= l_loc) ? sac[m][np][r] * __expf(dal[r] - dAs) : 0.f;
                        pvs[(4 * g + r) * 72 + 16 * np + c] = f2bf(v);
                    }
                }
                bf16x8 pa0 = *(const bf16x8*)&pvs[c * 72 + 8 * g];
                bf16x8 pa1 = *(const bf16x8*)&pvs[c * 72 + 32 + 8 * g];
                #pragma unroll
                for (int np = 0; np < 4; np++) {
                    yac[m][np] = MFMA_OP(pa0, xb[np][0], yac[m][np], 0, 0, 0);
                    yac[m][np] = MFMA_OP(pa1, xb[np][1], yac[m][np], 0, 0, 0);
                }
            }
        }
    }
    #pragma unroll
    for (int m = 0; m < 4; m++)
        #pragma unroll
        for (int np = 0; np < 4; np++)
            #pragma unroll
            for (int r = 0; r < 4; r++) {
                int l = wbase + m * 16 + 4 * g + r;
                y[(size_t)(rowbase + l) * DINNER + h * 64 + 16 * np + c] = f2bf(yac[m][np][r]);
            }
}

// ============================================================
// gated grouped RMSNorm (in place over y), adds D*x first.
// ============================================================
__global__ void norm_kernel(ushort* __restrict__ y, const ushort* __restrict__ zbuf,
                            const ushort* __restrict__ convout, const float* __restrict__ Dvec,
                            const float* __restrict__ nw) {
    int row = blockIdx.x;
    int g = blockIdx.y * 4 + (threadIdx.x >> 6);
    int lane = threadIdx.x & 63;
    int cbase = g * 128 + lane * 2;
    int h = cbase >> 6;
    int p = cbase & 63;
    int xc = ((h >> 3) << 7) + ((h & 1) << 6) + p;
    uint yv = *(const uint*)&y[(size_t)row * DINNER + cbase];
    uint zv = *(const uint*)&zbuf[(size_t)row * DINNER + cbase];
    uint xv = *(const uint*)&convout[(size_t)row * CONVDIM + xc];
    float Dh = Dvec[h];
    float y0 = bflo(yv) + Dh * bflo(xv), y1 = bfhi(yv) + Dh * bfhi(xv);
    float z0 = bflo(zv), z1 = bfhi(zv);
    float v0 = y0 * (z0 / (1.f + __expf(-z0)));
    float v1 = y1 * (z1 / (1.f + __expf(-z1)));
    float ss = v0 * v0 + v1 * v1;
    #pragma unroll
    for (int off = 32; off; off >>= 1) ss += __shfl_xor(ss, off, 64);
    float rstd = rsqrtf(ss * (1.f / 128.f) + 1e-5f);
    v0 *= rstd * nw[cbase];
    v1 *= rstd * nw[cbase + 1];
    *(uint*)&y[(size_t)row * DINNER + cbase] = pk2(v0, v1);
}

// ============================================================
extern "C" void kernel_launch(void* const* d_in, const int* in_sizes, int n_in,
                              void* d_out, int out_size, void* d_ws, size_t ws_size,
                              hipStream_t stream) {
    const float* u       = (const float*)d_in[0];
    const float* W_in    = (const float*)d_in[1];
    const float* conv_w  = (const float*)d_in[2];
    const float* conv_b  = (const float*)d_in[3];
    const float* dt_bias = (const float*)d_in[4];
    const float* A_log   = (const float*)d_in[5];
    const float* Dvec    = (const float*)d_in[6];
    const float* nw      = (const float*)d_in[7];
    const float* W_out   = (const float*)d_in[8];

    // ---- workspace layout (~196 MiB) ----
    char* ws = (char*)d_ws;
    size_t off = 0;
    auto alloc = [&](size_t bytes) { void* p = ws + off; off += (bytes + 255) & ~(size_t)255; return p; };
    ushort* zbuf    = (ushort*)alloc((size_t)LTOT * DINNER * 2);          // 32 MiB
    void*   shreg   = alloc((size_t)LTOT * CONVDIM * 2);                  // 48 MiB
    ushort* xbc     = (ushort*)shreg;
    float*  states  = (float*)shreg;
    float*  dtbuf   = (float*) alloc((size_t)LTOT * 64 * 4);              // 1 MiB
    void*   convreg = alloc((size_t)LTOT * CONVDIM * 2);                  // 48 MiB
    ushort* Win_bf  = (ushort*)convreg;
    ushort* convout = (ushort*)convreg;
    float*  dAcs    = (float*) alloc((size_t)1024 * 256 * 4);             // 1 MiB
    void*   ybreg   = alloc((size_t)LTOT * DINNER * 2);                   // 32 MiB
    ushort* u_bf    = (ushort*)ybreg;
    ushort* ybuf    = (ushort*)ybreg;
    ushort* Wout_bf = (ushort*)alloc((size_t)DMODEL * DINNER * 2);        // 17 MiB

    // fused bf16 conversions (one launch: u, W_in, W_out)
    cvt_all<<<dim3(36992), dim3(256), 0, stream>>>(u, W_in, W_out, u_bf, Win_bf, Wout_bf);
    // in_proj: 128x256 pipelined kernel; grid 32 bm x 41 bn = 1312 (%8==0)
    gemm_in<<<dim3(1312), dim3(512), 0, stream>>>(u_bf, Win_bf, zbuf, xbc, dtbuf);
    // conv + silu
    conv_kernel<<<dim3(3, 1024), dim3(256), 0, stream>>>(xbc, conv_w, conv_b, convout);
    // fused softplus + cumsum
    cumsum_kernel<<<dim3(1024), dim3(256), 0, stream>>>(dtbuf, dt_bias, A_log, dAcs);
    // chunked scan
    states_mfma<<<dim3(1024), dim3(256), 0, stream>>>(convout, dtbuf, dAcs, states);
    recur_kernel<<<dim3(1024), dim3(256), 0, stream>>>(dAcs, states);
    yscan_mfma<<<dim3(1024), dim3(256), 0, stream>>>(convout, dtbuf, dAcs, states, ybuf);
    // gated group RMSNorm
    norm_kernel<<<dim3(4096, 8), dim3(256), 0, stream>>>(ybuf, zbuf, convout, Dvec, nw);
    // out_proj: pre-read pipelined kernel; grid 256 (1/CU exact)
    gemm256_out<<<dim3(256), dim3(512), 0, stream>>>(ybuf, Wout_bf, (float*)d_out);
}

// Round 15
// 459.041 us; speedup vs baseline: 1.0835x; 1.0835x over previous
//
#include <hip/hip_runtime.h>
#include <cstdint>
#include <cstddef>

typedef unsigned int uint;
typedef unsigned short ushort;

typedef __bf16 bf16x8 __attribute__((ext_vector_type(8)));
typedef float f32x4 __attribute__((ext_vector_type(4)));

// ---------- bf16 helpers (bit-level) ----------
__device__ __forceinline__ float bflo(uint u) { return __uint_as_float(u << 16); }
__device__ __forceinline__ float bfhi(uint u) { return __uint_as_float(u & 0xffff0000u); }
__device__ __forceinline__ float bf2f(ushort s) { return __uint_as_float(((uint)s) << 16); }
__device__ __forceinline__ ushort f2bf(float f) {
    uint u = __float_as_uint(f);
    u += 0x7fffu + ((u >> 16) & 1u);   // round-to-nearest-even
    return (ushort)(u >> 16);
}
__device__ __forceinline__ uint pk2(float lo, float hi) {
    return (uint)f2bf(lo) | ((uint)f2bf(hi) << 16);
}
__device__ __forceinline__ void unpack8(uint4 v, float* f) {
    f[0] = bflo(v.x); f[1] = bfhi(v.x); f[2] = bflo(v.y); f[3] = bfhi(v.y);
    f[4] = bflo(v.z); f[5] = bfhi(v.z); f[6] = bflo(v.w); f[7] = bfhi(v.w);
}

// async global->LDS, 16B per lane, wave-uniform LDS base (linear dest)
typedef __attribute__((address_space(1))) const unsigned int* as1_cuptr;
typedef __attribute__((address_space(3))) unsigned int* as3_uptr;
__device__ __forceinline__ void gload_lds16(const void* g, void* l) {
    __builtin_amdgcn_global_load_lds((as1_cuptr)g, (as3_uptr)l, 16, 0, 0);
}

// ---------- constants ----------
#define LTOT 4096           // b*l tokens (2 batches x 2048)
#define DMODEL 2048
#define DINNER 4096
#define DSTATE 128
#define NHEADS 64
#define CONVDIM 6144
#define DPROJ 10304
#define CHUNK 256
#define NCHUNK 16           // GLOBAL chunks (8 per batch x 2 batches)

// ============================================================
// fused fp32 -> bf16 conversion for u, W_in, W_out (one launch)
// ============================================================
__global__ void cvt_all(const float* __restrict__ u, const float* __restrict__ Wi,
                        const float* __restrict__ Wo, ushort* __restrict__ ub,
                        ushort* __restrict__ wib, ushort* __restrict__ wob) {
    int i = blockIdx.x * 256 + threadIdx.x;   // float4 index
    const float* src; ushort* dst; int j;
    if (i < 2097152)      { src = u;  dst = ub;  j = i; }
    else if (i < 7372800) { src = Wi; dst = wib; j = i - 2097152; }
    else if (i < 9469952) { src = Wo; dst = wob; j = i - 7372800; }
    else return;
    float4 v = ((const float4*)src)[j];
    ushort4 o;
    o.x = f2bf(v.x); o.y = f2bf(v.y); o.z = f2bf(v.z); o.w = f2bf(v.w);
    ((ushort4*)dst)[j] = o;
}

// ============================================================
// in_proj: 256x256-tile 8-phase GEMM, BK=64, ONE-PHASE-AHEAD pre-read
// (EXACT round-13 kernel — verified 196 us, MfmaUtil 39%, 0 conflicts)
// ============================================================
#define MFMA_OP __builtin_amdgcn_mfma_f32_16x16x32_bf16
#define MMX(MB, AV, BV) do { \
  _Pragma("unroll") \
  for (int _m = 0; _m < 4; _m++) \
    _Pragma("unroll") \
    for (int _n = 0; _n < 4; _n++) \
      acc[(MB)+_m][_n] = MFMA_OP(AV[_m], BV[_n], acc[(MB)+_m][_n], 0, 0, 0); \
} while (0)

#define RD8(BASE, OFF) (*(const bf16x8*)((BASE) + (OFF)))

__global__ __launch_bounds__(512, 2) void gemm256_in(
    const ushort* __restrict__ X, const ushort* __restrict__ W,
    ushort* __restrict__ zbuf, ushort* __restrict__ xbc, float* __restrict__ dtraw) {
    __shared__ ushort AL[2][16384];   // [buf][2 panels x 8192 elems]
    __shared__ ushort BL[2][16384];
    const int NBN = 41;
    int q = gridDim.x >> 3;                 // 82
    int wg = blockIdx.x;
    int swz = (wg & 7) * q + (wg >> 3);
    int per = NBN * 4;                      // 164
    int sg = swz / per, rr = swz % per;
    int bm = sg * 4 + (rr & 3);
    int bn = rr >> 2;
    int tid = threadIdx.x;
    int lane = tid & 63, w = tid >> 6;
    int wr = w >> 2, wc = w & 3;
    int lr = lane & 15, g = lane >> 4;
    int y00 = ((lr >> 1) << 7) | ((lr & 1) << 6) | (g << 4);
    int z00 = y00 ^ (((y00 >> 7) & 7) << 4);
    int aBase = wr * 8192 + z00;
    int bBase = wc * 4096 + z00;
    int z0 = tid * 16, z1 = z0 + 8192;
    int y0 = z0 ^ (((z0 >> 7) & 7) << 4);
    int y1 = z1 ^ (((z1 >> 7) & 7) << 4);
    int row0s = ((y0 >> 7) << 1) | ((y0 >> 6) & 1), kbe0 = (y0 & 63) >> 1;
    int row1s = ((y1 >> 7) << 1) | ((y1 >> 6) & 1), kbe1 = (y1 & 63) >> 1;
    const ushort* gA0 = &X[(size_t)(bm * 256 + row0s) * 2048 + kbe0];
    const ushort* gA1 = &X[(size_t)(bm * 256 + row1s) * 2048 + kbe1];
    const ushort* gB0 = &W[(size_t)(bn * 256 + row0s) * 2048 + kbe0];
    const ushort* gB1 = &W[(size_t)(bn * 256 + row1s) * 2048 + kbe1];
    int wOff = w * 1024;

#define STAGE(DB, ARR, KP, P0, P1, KO) do { \
    gload_lds16((P0) + (KO) + (KP) * 32, (char*)(ARR) + (DB) * 32768 + (KP) * 16384 + wOff); \
    gload_lds16((P1) + (KO) + (KP) * 32, (char*)(ARR) + (DB) * 32768 + (KP) * 16384 + wOff + 8192); \
} while (0)

    f32x4 acc[8][4] = {};
    bf16x8 bLo[4], bHi[4], aE[4], aO[4];
    STAGE(0, AL, 0, gA0, gA1, 0);
    STAGE(0, BL, 0, gB0, gB1, 0);
    STAGE(0, AL, 1, gA0, gA1, 0);
    STAGE(0, BL, 1, gB0, gB1, 0);
    asm volatile("s_waitcnt vmcnt(4)" ::: "memory");
    __builtin_amdgcn_s_barrier();
    __builtin_amdgcn_sched_barrier(0);
    {
        const char* Ab = (const char*)AL;
        const char* Bb = (const char*)BL;
        #pragma unroll
        for (int i = 0; i < 4; i++) {
            bLo[i] = RD8(Bb, bBase + i * 1024);
            aE[i]  = RD8(Ab, aBase + i * 1024);
        }
    }

    for (int t = 0; t < 32; ++t) {
        int buf = t & 1, nb = buf ^ 1;
        int ko = ((t + 1) & 31) * 64;
        const char* Ab  = (const char*)AL + buf * 32768;
        const char* Bb  = (const char*)BL + buf * 32768;
        const char* AbN = (const char*)AL + nb * 32768;
        const char* BbN = (const char*)BL + nb * 32768;
        // ---- phase A ----
        #pragma unroll
        for (int i = 0; i < 4; i++) aO[i] = RD8(Ab, aBase + 4096 + i * 1024);
        STAGE(nb, AL, 0, gA0, gA1, ko);
        __builtin_amdgcn_s_setprio(1);
        MMX(0, aE, bLo);
        __builtin_amdgcn_s_setprio(0);
        __builtin_amdgcn_sched_barrier(0);
        // ---- phase B ----
        asm volatile("s_waitcnt vmcnt(2)" ::: "memory");
        __builtin_amdgcn_s_barrier();
        __builtin_amdgcn_sched_barrier(0);
        #pragma unroll
        for (int i = 0; i < 4; i++) {
            bHi[i] = RD8(Bb, bBase + 16384 + i * 1024);
            aE[i]  = RD8(Ab, aBase + 16384 + i * 1024);
        }
        STAGE(nb, BL, 0, gB0, gB1, ko);
        __builtin_amdgcn_s_setprio(1);
        MMX(4, aO, bLo);
        __builtin_amdgcn_s_setprio(0);
        __builtin_amdgcn_sched_barrier(0);
        // ---- phase C ----
        #pragma unroll
        for (int i = 0; i < 4; i++) aO[i] = RD8(Ab, aBase + 16384 + 4096 + i * 1024);
        STAGE(nb, AL, 1, gA0, gA1, ko);
        __builtin_amdgcn_s_setprio(1);
        MMX(0, aE, bHi);
        __builtin_amdgcn_s_setprio(0);
        __builtin_amdgcn_sched_barrier(0);
        // ---- phase D ----
        asm volatile("s_waitcnt vmcnt(2)" ::: "memory");
        __builtin_amdgcn_s_barrier();
        __builtin_amdgcn_sched_barrier(0);
        #pragma unroll
        for (int i = 0; i < 4; i++) {
            bLo[i] = RD8(BbN, bBase + i * 1024);
            aE[i]  = RD8(AbN, aBase + i * 1024);
        }
        STAGE(nb, BL, 1, gB0, gB1, ko);
        __builtin_amdgcn_s_setprio(1);
        MMX(4, aO, bHi);
        __builtin_amdgcn_s_setprio(0);
        __builtin_amdgcn_sched_barrier(0);
    }
    asm volatile("s_waitcnt vmcnt(0)" ::: "memory");

    int rq = g * 4;
    #pragma unroll
    for (int mf = 0; mf < 8; mf++) {
        int row0 = bm * 256 + wr * 128 + mf * 16 + rq;
        #pragma unroll
        for (int n = 0; n < 4; n++) {
            int cb0 = bn * 256 + wc * 64 + n * 16;
            int col = cb0 + lr;
            if (cb0 < 4096) {
                #pragma unroll
                for (int r = 0; r < 4; r++)
                    zbuf[(size_t)(row0 + r) * DINNER + col] = f2bf(acc[mf][n][r]);
            } else if (cb0 < 10240) {
                #pragma unroll
                for (int r = 0; r < 4; r++)
                    xbc[(size_t)(row0 + r) * CONVDIM + (col - 4096)] = f2bf(acc[mf][n][r]);
            } else if (cb0 < 10304) {
                #pragma unroll
                for (int r = 0; r < 4; r++)
                    dtraw[(size_t)(row0 + r) * 64 + (col - 10240)] = acc[mf][n][r];
            }
        }
    }
}
#undef STAGE

// ============================================================
// out_proj: 256x128-tile pipelined GEMM with pre-read (round 13, verified)
// ============================================================
#define MM8(M0, AV, BV) do { \
  _Pragma("unroll") \
  for (int _m = 0; _m < 2; _m++) \
    _Pragma("unroll") \
    for (int _n = 0; _n < 4; _n++) \
      acc[(M0)+_m][_n] = MFMA_OP(AV[(M0)+_m], BV[_n], acc[(M0)+_m][_n], 0, 0, 0); \
} while (0)

__global__ __launch_bounds__(512, 2) void gemm256_out(
    const ushort* __restrict__ X, const ushort* __restrict__ W,
    float* __restrict__ outF) {
    __shared__ ushort AL[2][16384];
    __shared__ ushort BL[2][8192];
    int q = gridDim.x >> 3;
    int wg = blockIdx.x;
    int swz = (wg & 7) * q + (wg >> 3);
    int per = 16 * 4;
    int sg = swz / per, rr = swz % per;
    int bm = sg * 4 + (rr & 3);
    int bn = rr >> 2;
    int tid = threadIdx.x;
    int lane = tid & 63, w = tid >> 6;
    int wr = w >> 1, wc = w & 1;
    int lr = lane & 15, g = lane >> 4;
    int y00 = ((lr >> 1) << 7) | ((lr & 1) << 6) | (g << 4);
    int z00 = y00 ^ (((y00 >> 7) & 7) << 4);
    int aBase = wr * 4096 + z00;
    int bBase = wc * 4096 + z00;
    int z0 = tid * 16, z1 = z0 + 8192;
    int y0 = z0 ^ (((z0 >> 7) & 7) << 4);
    int y1 = z1 ^ (((z1 >> 7) & 7) << 4);
    int rowA0 = ((y0 >> 7) << 1) | ((y0 >> 6) & 1), kA0 = (y0 & 63) >> 1;
    int rowA1 = ((y1 >> 7) << 1) | ((y1 >> 6) & 1), kA1 = (y1 & 63) >> 1;
    const ushort* gA0 = &X[(size_t)(bm * 256 + rowA0) * 4096 + kA0];
    const ushort* gA1 = &X[(size_t)(bm * 256 + rowA1) * 4096 + kA1];
    const ushort* gB  = &W[(size_t)(bn * 128 + rowA0) * 4096 + kA0];
    int wOff = w * 1024;

#define STAGEA(DB, KP, KO) do { \
    gload_lds16(gA0 + (KO) + (KP) * 32, (char*)AL + (DB) * 32768 + (KP) * 16384 + wOff); \
    gload_lds16(gA1 + (KO) + (KP) * 32, (char*)AL + (DB) * 32768 + (KP) * 16384 + wOff + 8192); \
} while (0)
#define STAGEB(DB, KP, KO) \
    gload_lds16(gB + (KO) + (KP) * 32, (char*)BL + (DB) * 16384 + (KP) * 8192 + wOff)

    f32x4 acc[4][4] = {};
    bf16x8 aP[4], bP[4], aQ[4], bQ[4];
    STAGEA(0, 0, 0); STAGEB(0, 0, 0);
    STAGEA(0, 1, 0); STAGEB(0, 1, 0);
    asm volatile("s_waitcnt vmcnt(3)" ::: "memory");
    __builtin_amdgcn_s_barrier();
    __builtin_amdgcn_sched_barrier(0);
    #pragma unroll
    for (int i = 0; i < 4; i++) {
        bP[i] = RD8((const char*)BL, bBase + i * 1024);
        aP[i] = RD8((const char*)AL, aBase + i * 1024);
    }

    for (int t = 0; t < 64; ++t) {
        int buf = t & 1, nb = buf ^ 1;
        int ko = ((t + 1) & 63) * 64;
        const char* Ab  = (const char*)AL + buf * 32768;
        const char* Bb  = (const char*)BL + buf * 16384;
        const char* AbN = (const char*)AL + nb * 32768;
        const char* BbN = (const char*)BL + nb * 16384;
        STAGEA(nb, 0, ko); STAGEB(nb, 0, ko);
        __builtin_amdgcn_s_setprio(1);
        MM8(0, aP, bP);
        MM8(2, aP, bP);
        __builtin_amdgcn_s_setprio(0);
        __builtin_amdgcn_sched_barrier(0);
        asm volatile("s_waitcnt vmcnt(3)" ::: "memory");
        __builtin_amdgcn_s_barrier();
        __builtin_amdgcn_sched_barrier(0);
        #pragma unroll
        for (int i = 0; i < 4; i++) {
            bQ[i] = RD8(Bb, bBase + 8192 + i * 1024);
            aQ[i] = RD8(Ab, aBase + 16384 + i * 1024);
        }
        STAGEA(nb, 1, ko); STAGEB(nb, 1, ko);
        __builtin_amdgcn_s_setprio(1);
        MM8(0, aQ, bQ);
        __builtin_amdgcn_s_setprio(0);
        __builtin_amdgcn_sched_barrier(0);
        asm volatile("s_waitcnt vmcnt(3)" ::: "memory");
        __builtin_amdgcn_s_barrier();
        __builtin_amdgcn_sched_barrier(0);
        #pragma unroll
        for (int i = 0; i < 4; i++) {
            bP[i] = RD8(BbN, bBase + i * 1024);
            aP[i] = RD8(AbN, aBase + i * 1024);
        }
        __builtin_amdgcn_s_setprio(1);
        MM8(2, aQ, bQ);
        __builtin_amdgcn_s_setprio(0);
        __builtin_amdgcn_sched_barrier(0);
    }
    asm volatile("s_waitcnt vmcnt(0)" ::: "memory");

    int rq = g * 4;
    #pragma unroll
    for (int mf = 0; mf < 4; mf++) {
        int row0 = bm * 256 + wr * 64 + mf * 16 + rq;
        #pragma unroll
        for (int nf = 0; nf < 4; nf++) {
            int col = bn * 128 + wc * 64 + nf * 16 + lr;
            #pragma unroll
            for (int r = 0; r < 4; r++)
                outF[(size_t)(row0 + r) * DMODEL + col] = acc[mf][nf][r];
        }
    }
}
#undef STAGEA
#undef STAGEB

// ============================================================
// causal depthwise conv1d (K=4) + SiLU: 4 rows x 8 ch per thread
// ============================================================
__global__ void conv_kernel(const ushort* __restrict__ xbc, const float* __restrict__ cw,
                            const float* __restrict__ cb, ushort* __restrict__ convout) {
    int c8 = (blockIdx.x * 256 + threadIdx.x) * 8;
    int row0 = blockIdx.y * 4;
    int t0 = row0 & 2047;
    float bias[8];
    {
        float4 b0 = ((const float4*)cb)[c8 / 4];
        float4 b1 = ((const float4*)cb)[c8 / 4 + 1];
        bias[0] = b0.x; bias[1] = b0.y; bias[2] = b0.z; bias[3] = b0.w;
        bias[4] = b1.x; bias[5] = b1.y; bias[6] = b1.z; bias[7] = b1.w;
    }
    float wk[8][4];
    #pragma unroll
    for (int e = 0; e < 8; e++) {
        float4 wv = ((const float4*)cw)[c8 + e];
        wk[e][0] = wv.x; wk[e][1] = wv.y; wk[e][2] = wv.z; wk[e][3] = wv.w;
    }
    float f[7][8];
    #pragma unroll
    for (int j = 0; j < 7; j++) {
        int tt = t0 - 3 + j;
        if (tt >= 0) {
            uint4 v = *(const uint4*)&xbc[(size_t)(row0 - 3 + j) * CONVDIM + c8];
            unpack8(v, f[j]);
        } else {
            #pragma unroll
            for (int e = 0; e < 8; e++) f[j][e] = 0.f;
        }
    }
    #pragma unroll
    for (int r = 0; r < 4; r++) {
        float a[8];
        #pragma unroll
        for (int e = 0; e < 8; e++) {
            a[e] = bias[e];
            #pragma unroll
            for (int k = 0; k < 4; k++) a[e] += f[r + k][e] * wk[e][k];
        }
        uint4 o;
        float s[8];
        #pragma unroll
        for (int e = 0; e < 8; e++) s[e] = a[e] / (1.f + __expf(-a[e]));
        o.x = pk2(s[0], s[1]); o.y = pk2(s[2], s[3]);
        o.z = pk2(s[4], s[5]); o.w = pk2(s[6], s[7]);
        *(uint4*)&convout[(size_t)(row0 + r) * CONVDIM + c8] = o;
    }
}

// ============================================================
// fused: softplus(dtraw+bias) (in place) + per-chunk cumsum of dt*A
// ============================================================
__global__ void cumsum_kernel(float* __restrict__ dtbuf, const float* __restrict__ dt_bias,
                              const float* __restrict__ A_log, float* __restrict__ dAcs) {
    int bi = blockIdx.x;
    int h = bi & 63, cg = bi >> 6;
    int t = threadIdx.x;
    size_t didx = (size_t)(cg * 256 + t) * 64 + h;
    float x = dtbuf[didx] + dt_bias[h];
    float sp = (x > 20.f) ? x : log1pf(__expf(x));
    dtbuf[didx] = sp;
    float A = -expf(A_log[h]);
    float v = sp * A;
    __shared__ float s[256];
    s[t] = v;
    __syncthreads();
    for (int off = 1; off < 256; off <<= 1) {
        float add = (t >= off) ? s[t - off] : 0.f;
        __syncthreads();
        s[t] += add;
        __syncthreads();
    }
    dAcs[(size_t)bi * 256 + t] = s[t];
}

// ============================================================
// MFMA states: per (cg,h), states[p][n] = sum_s xdt'[s,p] * B[s,n]
// ============================================================
__global__ __launch_bounds__(256) void states_mfma(
    const ushort* __restrict__ convout, const float* __restrict__ dtsp,
    const float* __restrict__ dAcs, float* __restrict__ states) {
    __shared__ ushort BT[128 * 72];
    __shared__ ushort XT[64 * 72];
    int bi = blockIdx.x;
    int h = bi & 63, cg = bi >> 6;
    int tid = threadIdx.x;
    int rowbase = cg * 256;
    int bcol = 1024 + ((h >> 3) << 7);
    int xcol = ((h >> 3) << 7) + ((h & 1) << 6);
    float dAlast = dAcs[(size_t)bi * 256 + 255];
    int w = tid >> 6, lane = tid & 63, g = lane >> 4, cc = lane & 15;
    f32x4 acc[4][2] = {};
    for (int T = 0; T < 4; T++) {
        __syncthreads();
        int s = lane;
        int srow = rowbase + T * 64 + s;
        #pragma unroll
        for (int i = 0; i < 4; i++) {
            int n0 = (w + i * 4) * 8;
            uint4 v = *(const uint4*)&convout[(size_t)srow * CONVDIM + bcol + n0];
            ushort us[8];
            us[0] = (ushort)v.x; us[1] = (ushort)(v.x >> 16);
            us[2] = (ushort)v.y; us[3] = (ushort)(v.y >> 16);
            us[4] = (ushort)v.z; us[5] = (ushort)(v.z >> 16);
            us[6] = (ushort)v.w; us[7] = (ushort)(v.w >> 16);
            #pragma unroll
            for (int e = 0; e < 8; e++) BT[(n0 + e) * 72 + s] = us[e];
        }
        float wgt = dtsp[(size_t)srow * 64 + h] * __expf(dAlast - dAcs[(size_t)bi * 256 + T * 64 + s]);
        #pragma unroll
        for (int j = 0; j < 2; j++) {
            int p0 = (w * 2 + j) * 8;
            uint4 v = *(const uint4*)&convout[(size_t)srow * CONVDIM + xcol + p0];
            float f[8]; unpack8(v, f);
            #pragma unroll
            for (int e = 0; e < 8; e++) XT[(p0 + e) * 72 + s] = f2bf(f[e] * wgt);
        }
        __syncthreads();
        bf16x8 af[4][2], bw[2][2];
        #pragma unroll
        for (int m = 0; m < 4; m++)
            #pragma unroll
            for (int kb = 0; kb < 2; kb++)
                af[m][kb] = *(const bf16x8*)&XT[(m * 16 + cc) * 72 + kb * 32 + 8 * g];
        #pragma unroll
        for (int np = 0; np < 2; np++)
            #pragma unroll
            for (int kb = 0; kb < 2; kb++)
                bw[np][kb] = *(const bf16x8*)&BT[(w * 32 + np * 16 + cc) * 72 + kb * 32 + 8 * g];
        #pragma unroll
        for (int m = 0; m < 4; m++)
            #pragma unroll
            for (int np = 0; np < 2; np++) {
                acc[m][np] = MFMA_OP(af[m][0], bw[np][0], acc[m][np], 0, 0, 0);
                acc[m][np] = MFMA_OP(af[m][1], bw[np][1], acc[m][np], 0, 0, 0);
            }
    }
    size_t base = (size_t)bi * 8192;
    #pragma unroll
    for (int m = 0; m < 4; m++)
        #pragma unroll
        for (int np = 0; np < 2; np++)
            #pragma unroll
            for (int r = 0; r < 4; r++) {
                int p = m * 16 + 4 * g + r;
                int n = w * 32 + np * 16 + cc;
                states[base + (size_t)p * 128 + n] = acc[m][np][r];
            }
}

// ============================================================
// inter-chunk recurrence: 8 chunks PER BATCH, carry resets per batch
// ============================================================
__global__ void recur_kernel(const float* __restrict__ dAcs, float* __restrict__ states) {
    int blk = blockIdx.x;
    int pq = blk & 7, bh = blk >> 3;
    int h = bh & 63, b = bh >> 6;
    int tid = threadIdx.x;
    int p = pq * 8 + (tid >> 5);
    int n0 = (tid & 31) * 4;
    float4 carry = make_float4(0.f, 0.f, 0.f, 0.f);
    for (int c = 0; c < 8; c++) {
        int bi = (b * 8 + c) * 64 + h;
        float decay = __expf(dAcs[(size_t)bi * 256 + 255]);
        size_t idx = (size_t)bi * 8192 + (size_t)p * 128 + n0;
        float4 tmp = *(const float4*)&states[idx];
        *(float4*)&states[idx] = carry;
        carry.x = carry.x * decay + tmp.x;
        carry.y = carry.y * decay + tmp.y;
        carry.z = carry.z * decay + tmp.z;
        carry.w = carry.w * decay + tmp.w;
    }
}

// ============================================================
// MFMA yscan (WAVE-BALANCED): wave w owns l-rows m*64 + 16w + [0,16)
// for m=0..3 — every wave processes 10 tile-units (was 1:2:3:4).
// Decay per m-group: Sm = sdA[m*64]; all factors <= 1 (cumsum
// monotonically decreasing; m>T => Sm <= ET; l >= m*64 => dAl <= Sm).
// Diagonal tile (m==T): direct masked exp (arg <= 0 where kept).
// ============================================================
__global__ __launch_bounds__(256, 2) void yscan_mfma(
    const ushort* __restrict__ convout, const float* __restrict__ dtsp,
    const float* __restrict__ dAcs, const float* __restrict__ states,
    ushort* __restrict__ y) {
    __shared__ ushort XT[64 * 264];
    __shared__ ushort PR[64 * 136];
    __shared__ ushort PV[4 * 16 * 72];
    __shared__ float sdA[256];
    int bi = blockIdx.x;
    int h = bi & 63, cg = bi >> 6;
    int tid = threadIdx.x;
    int rowbase = cg * 256;
    int bcol = 1024 + ((h >> 3) << 7);
    int ccol = 2048 + ((h >> 1) << 7);
    int xcol = ((h >> 3) << 7) + ((h & 1) << 6);

    sdA[tid] = dAcs[(size_t)bi * 256 + tid];
    #pragma unroll
    for (int i = 0; i < 4; i++) {
        int s = i * 64 + (tid & 63);
        float dtv = dtsp[(size_t)(rowbase + s) * 64 + h];
        #pragma unroll
        for (int j = 0; j < 2; j++) {
            int p0 = (((tid >> 6) << 1) + j) << 3;
            uint4 v = *(const uint4*)&convout[(size_t)(rowbase + s) * CONVDIM + xcol + p0];
            float f[8]; unpack8(v, f);
            #pragma unroll
            for (int e = 0; e < 8; e++) XT[(p0 + e) * 264 + s] = f2bf(f[e] * dtv);
        }
    }
    {
        const float* pv = &states[(size_t)bi * 8192];
        #pragma unroll
        for (int i = 0; i < 8; i++) {
            int flat = i * 1024 + tid * 4;
            float4 v = *(const float4*)&pv[flat];
            int p = flat >> 7, n = flat & 127;
            *(uint*)&PR[p * 136 + n]     = pk2(v.x, v.y);
            *(uint*)&PR[p * 136 + n + 2] = pk2(v.z, v.w);
        }
    }
    __syncthreads();

    int w = tid >> 6, lane = tid & 63, g = lane >> 4, c = lane & 15;
    // wave w handles l-rows m*64 + 16w + {0..15}, m = 0..3 (balanced)
    const ushort* Crow0 = &convout[(size_t)(rowbase + w * 16 + c) * CONVDIM + ccol + 8 * g];

    // ---- Y_off = C . prev^T ----
    f32x4 yac[4][4] = {};
    #pragma unroll
    for (int kb = 0; kb < 4; kb++) {
        bf16x8 pb[4];
        #pragma unroll
        for (int np = 0; np < 4; np++)
            pb[np] = *(const bf16x8*)&PR[(16 * np + c) * 136 + kb * 32 + 8 * g];
        #pragma unroll
        for (int m = 0; m < 4; m++) {
            bf16x8 cf = *(const bf16x8*)&Crow0[(size_t)(m * 64) * CONVDIM + kb * 32];
            #pragma unroll
            for (int np = 0; np < 4; np++)
                yac[m][np] = MFMA_OP(cf, pb[np], yac[m][np], 0, 0, 0);
        }
    }
    // scale by exp(dA_l) = al[m][r] * exp(Sm); both factors <= 1
    float al[4][4];
    #pragma unroll
    for (int m = 0; m < 4; m++) {
        float Sm = sdA[m * 64];
        float eSm = __expf(Sm);
        #pragma unroll
        for (int r = 0; r < 4; r++) {
            float dAl = sdA[m * 64 + w * 16 + 4 * g + r];
            al[m][r] = __expf(dAl - Sm);
            float el = al[m][r] * eSm;
            #pragma unroll
            for (int np = 0; np < 4; np++) yac[m][np][r] *= el;
        }
    }

    // ---- s-tiles: T outer, m in [T,4) inner (balanced across waves) ----
    ushort* pvs = &PV[w * 1152];
    #pragma unroll
    for (int T = 0; T < 4; T++) {
        // B tile T into regs (read once per T)
        bf16x8 bbT[4][4];   // [kb][np]
        #pragma unroll
        for (int kb = 0; kb < 4; kb++)
            #pragma unroll
            for (int np = 0; np < 4; np++)
                bbT[kb][np] = *(const bf16x8*)&convout[(size_t)(rowbase + T * 64 + 16 * np + c) * CONVDIM + bcol + kb * 32 + 8 * g];
        bf16x8 xb[4][2];
        #pragma unroll
        for (int np = 0; np < 4; np++)
            #pragma unroll
            for (int k2 = 0; k2 < 2; k2++)
                xb[np][k2] = *(const bf16x8*)&XT[(16 * np + c) * 264 + T * 64 + k2 * 32 + 8 * g];
        float ET = sdA[T * 64 + 63];
        #pragma unroll
        for (int m = 0; m < 4; m++) {
            if (m < T) continue;
            f32x4 sac[4] = {};
            #pragma unroll
            for (int kb = 0; kb < 4; kb++) {
                bf16x8 cf = *(const bf16x8*)&Crow0[(size_t)(m * 64) * CONVDIM + kb * 32];
                #pragma unroll
                for (int np = 0; np < 4; np++)
                    sac[np] = MFMA_OP(cf, bbT[kb][np], sac[np], 0, 0, 0);
            }
            if (m > T) {
                float cTm = __expf(sdA[m * 64] - ET);   // <= 1 (m>T)
                #pragma unroll
                for (int np = 0; np < 4; np++) {
                    float bcv = __expf(ET - sdA[T * 64 + 16 * np + c]) * cTm;
                    #pragma unroll
                    for (int r = 0; r < 4; r++)
                        pvs[(4 * g + r) * 72 + 16 * np + c] = f2bf(sac[np][r] * (al[m][r] * bcv));
                }
            } else {   // m == T: diagonal, masked direct exp
                float dal[4];
                #pragma unroll
                for (int r = 0; r < 4; r++) dal[r] = sdA[m * 64 + w * 16 + 4 * g + r];
                #pragma unroll
                for (int np = 0; np < 4; np++) {
                    int s_loc = m * 64 + 16 * np + c;
                    float dAs = sdA[s_loc];
                    #pragma unroll
                    for (int r = 0; r < 4; r++) {
                        int l_loc = m * 64 + w * 16 + 4 * g + r;
                        float v = (s_loc <= l_loc) ? sac[np][r] * __expf(dal[r] - dAs) : 0.f;
                        pvs[(4 * g + r) * 72 + 16 * np + c] = f2bf(v);
                    }
                }
            }
            bf16x8 pa0 = *(const bf16x8*)&pvs[c * 72 + 8 * g];
            bf16x8 pa1 = *(const bf16x8*)&pvs[c * 72 + 32 + 8 * g];
            #pragma unroll
            for (int np = 0; np < 4; np++) {
                yac[m][np] = MFMA_OP(pa0, xb[np][0], yac[m][np], 0, 0, 0);
                yac[m][np] = MFMA_OP(pa1, xb[np][1], yac[m][np], 0, 0, 0);
            }
        }
    }
    // ---- store: l = m*64 + 16w + 4g + r ----
    #pragma unroll
    for (int m = 0; m < 4; m++)
        #pragma unroll
        for (int np = 0; np < 4; np++)
            #pragma unroll
            for (int r = 0; r < 4; r++) {
                int l = m * 64 + w * 16 + 4 * g + r;
                y[(size_t)(rowbase + l) * DINNER + h * 64 + 16 * np + c] = f2bf(yac[m][np][r]);
            }
}

// ============================================================
// gated grouped RMSNorm (in place over y), adds D*x first.
// ============================================================
__global__ void norm_kernel(ushort* __restrict__ y, const ushort* __restrict__ zbuf,
                            const ushort* __restrict__ convout, const float* __restrict__ Dvec,
                            const float* __restrict__ nw) {
    int row = blockIdx.x;
    int g = blockIdx.y * 4 + (threadIdx.x >> 6);
    int lane = threadIdx.x & 63;
    int cbase = g * 128 + lane * 2;
    int h = cbase >> 6;
    int p = cbase & 63;
    int xc = ((h >> 3) << 7) + ((h & 1) << 6) + p;
    uint yv = *(const uint*)&y[(size_t)row * DINNER + cbase];
    uint zv = *(const uint*)&zbuf[(size_t)row * DINNER + cbase];
    uint xv = *(const uint*)&convout[(size_t)row * CONVDIM + xc];
    float Dh = Dvec[h];
    float y0 = bflo(yv) + Dh * bflo(xv), y1 = bfhi(yv) + Dh * bfhi(xv);
    float z0 = bflo(zv), z1 = bfhi(zv);
    float v0 = y0 * (z0 / (1.f + __expf(-z0)));
    float v1 = y1 * (z1 / (1.f + __expf(-z1)));
    float ss = v0 * v0 + v1 * v1;
    #pragma unroll
    for (int off = 32; off; off >>= 1) ss += __shfl_xor(ss, off, 64);
    float rstd = rsqrtf(ss * (1.f / 128.f) + 1e-5f);
    v0 *= rstd * nw[cbase];
    v1 *= rstd * nw[cbase + 1];
    *(uint*)&y[(size_t)row * DINNER + cbase] = pk2(v0, v1);
}

// ============================================================
extern "C" void kernel_launch(void* const* d_in, const int* in_sizes, int n_in,
                              void* d_out, int out_size, void* d_ws, size_t ws_size,
                              hipStream_t stream) {
    const float* u       = (const float*)d_in[0];
    const float* W_in    = (const float*)d_in[1];
    const float* conv_w  = (const float*)d_in[2];
    const float* conv_b  = (const float*)d_in[3];
    const float* dt_bias = (const float*)d_in[4];
    const float* A_log   = (const float*)d_in[5];
    const float* Dvec    = (const float*)d_in[6];
    const float* nw      = (const float*)d_in[7];
    const float* W_out   = (const float*)d_in[8];

    // ---- workspace layout (~196 MiB) ----
    char* ws = (char*)d_ws;
    size_t off = 0;
    auto alloc = [&](size_t bytes) { void* p = ws + off; off += (bytes + 255) & ~(size_t)255; return p; };
    ushort* zbuf    = (ushort*)alloc((size_t)LTOT * DINNER * 2);          // 32 MiB
    void*   shreg   = alloc((size_t)LTOT * CONVDIM * 2);                  // 48 MiB
    ushort* xbc     = (ushort*)shreg;
    float*  states  = (float*)shreg;
    float*  dtbuf   = (float*) alloc((size_t)LTOT * 64 * 4);              // 1 MiB
    void*   convreg = alloc((size_t)LTOT * CONVDIM * 2);                  // 48 MiB
    ushort* Win_bf  = (ushort*)convreg;
    ushort* convout = (ushort*)convreg;
    float*  dAcs    = (float*) alloc((size_t)1024 * 256 * 4);             // 1 MiB
    void*   ybreg   = alloc((size_t)LTOT * DINNER * 2);                   // 32 MiB
    ushort* u_bf    = (ushort*)ybreg;
    ushort* ybuf    = (ushort*)ybreg;
    ushort* Wout_bf = (ushort*)alloc((size_t)DMODEL * DINNER * 2);        // 17 MiB

    // fused bf16 conversions (one launch: u, W_in, W_out)
    cvt_all<<<dim3(36992), dim3(256), 0, stream>>>(u, W_in, W_out, u_bf, Win_bf, Wout_bf);
    // in_proj: round-13 proven pre-read kernel; grid 16 bm x 41 bn = 656
    gemm256_in<<<dim3(656), dim3(512), 0, stream>>>(u_bf, Win_bf, zbuf, xbc, dtbuf);
    // conv + silu
    conv_kernel<<<dim3(3, 1024), dim3(256), 0, stream>>>(xbc, conv_w, conv_b, convout);
    // fused softplus + cumsum
    cumsum_kernel<<<dim3(1024), dim3(256), 0, stream>>>(dtbuf, dt_bias, A_log, dAcs);
    // chunked scan
    states_mfma<<<dim3(1024), dim3(256), 0, stream>>>(convout, dtbuf, dAcs, states);
    recur_kernel<<<dim3(1024), dim3(256), 0, stream>>>(dAcs, states);
    yscan_mfma<<<dim3(1024), dim3(256), 0, stream>>>(convout, dtbuf, dAcs, states, ybuf);
    // gated group RMSNorm
    norm_kernel<<<dim3(4096, 8), dim3(256), 0, stream>>>(ybuf, zbuf, convout, Dvec, nw);
    // out_proj: pre-read pipelined kernel; grid 256 (1/CU exact)
    gemm256_out<<<dim3(256), dim3(512), 0, stream>>>(ybuf, Wout_bf, (float*)d_out);
}

// Round 16
// 443.679 us; speedup vs baseline: 1.1210x; 1.0346x over previous
//
#include <hip/hip_runtime.h>
#include <cstdint>
#include <cstddef>

typedef unsigned int uint;
typedef unsigned short ushort;

typedef __bf16 bf16x8 __attribute__((ext_vector_type(8)));
typedef float f32x4 __attribute__((ext_vector_type(4)));

// ---------- bf16 helpers (bit-level) ----------
__device__ __forceinline__ float bflo(uint u) { return __uint_as_float(u << 16); }
__device__ __forceinline__ float bfhi(uint u) { return __uint_as_float(u & 0xffff0000u); }
__device__ __forceinline__ float bf2f(ushort s) { return __uint_as_float(((uint)s) << 16); }
__device__ __forceinline__ ushort f2bf(float f) {
    uint u = __float_as_uint(f);
    u += 0x7fffu + ((u >> 16) & 1u);   // round-to-nearest-even
    return (ushort)(u >> 16);
}
__device__ __forceinline__ uint pk2(float lo, float hi) {
    return (uint)f2bf(lo) | ((uint)f2bf(hi) << 16);
}
__device__ __forceinline__ void unpack8(uint4 v, float* f) {
    f[0] = bflo(v.x); f[1] = bfhi(v.x); f[2] = bflo(v.y); f[3] = bfhi(v.y);
    f[4] = bflo(v.z); f[5] = bfhi(v.z); f[6] = bflo(v.w); f[7] = bfhi(v.w);
}

// async global->LDS, 16B per lane, wave-uniform LDS base (linear dest)
typedef __attribute__((address_space(1))) const unsigned int* as1_cuptr;
typedef __attribute__((address_space(3))) unsigned int* as3_uptr;
__device__ __forceinline__ void gload_lds16(const void* g, void* l) {
    __builtin_amdgcn_global_load_lds((as1_cuptr)g, (as3_uptr)l, 16, 0, 0);
}

// ---------- constants ----------
#define LTOT 4096           // b*l tokens (2 batches x 2048)
#define DMODEL 2048
#define DINNER 4096
#define DSTATE 128
#define NHEADS 64
#define CONVDIM 6144
#define DPROJ 10304
#define CHUNK 256
#define NCHUNK 16           // GLOBAL chunks (8 per batch x 2 batches)

// ============================================================
// fused fp32 -> bf16 conversion for u, W_in, W_out (one launch)
// ============================================================
__global__ void cvt_all(const float* __restrict__ u, const float* __restrict__ Wi,
                        const float* __restrict__ Wo, ushort* __restrict__ ub,
                        ushort* __restrict__ wib, ushort* __restrict__ wob) {
    int i = blockIdx.x * 256 + threadIdx.x;   // float4 index
    const float* src; ushort* dst; int j;
    if (i < 2097152)      { src = u;  dst = ub;  j = i; }
    else if (i < 7372800) { src = Wi; dst = wib; j = i - 2097152; }
    else if (i < 9469952) { src = Wo; dst = wob; j = i - 7372800; }
    else return;
    float4 v = ((const float4*)src)[j];
    ushort4 o;
    o.x = f2bf(v.x); o.y = f2bf(v.y); o.z = f2bf(v.z); o.w = f2bf(v.w);
    ((ushort4*)dst)[j] = o;
}

// ============================================================
// in_proj: 256x256-tile 8-phase GEMM, BK=64, ONE-PHASE-AHEAD pre-read
// (EXACT round-13 kernel — verified 196 us, MfmaUtil 39%, 0 conflicts)
// ============================================================
#define MFMA_OP __builtin_amdgcn_mfma_f32_16x16x32_bf16
#define MMX(MB, AV, BV) do { \
  _Pragma("unroll") \
  for (int _m = 0; _m < 4; _m++) \
    _Pragma("unroll") \
    for (int _n = 0; _n < 4; _n++) \
      acc[(MB)+_m][_n] = MFMA_OP(AV[_m], BV[_n], acc[(MB)+_m][_n], 0, 0, 0); \
} while (0)

#define RD8(BASE, OFF) (*(const bf16x8*)((BASE) + (OFF)))

__global__ __launch_bounds__(512, 2) void gemm256_in(
    const ushort* __restrict__ X, const ushort* __restrict__ W,
    ushort* __restrict__ zbuf, ushort* __restrict__ xbc, float* __restrict__ dtraw) {
    __shared__ ushort AL[2][16384];   // [buf][2 panels x 8192 elems]
    __shared__ ushort BL[2][16384];
    const int NBN = 41;
    int q = gridDim.x >> 3;                 // 82
    int wg = blockIdx.x;
    int swz = (wg & 7) * q + (wg >> 3);
    int per = NBN * 4;                      // 164
    int sg = swz / per, rr = swz % per;
    int bm = sg * 4 + (rr & 3);
    int bn = rr >> 2;
    int tid = threadIdx.x;
    int lane = tid & 63, w = tid >> 6;
    int wr = w >> 2, wc = w & 3;
    int lr = lane & 15, g = lane >> 4;
    int y00 = ((lr >> 1) << 7) | ((lr & 1) << 6) | (g << 4);
    int z00 = y00 ^ (((y00 >> 7) & 7) << 4);
    int aBase = wr * 8192 + z00;
    int bBase = wc * 4096 + z00;
    int z0 = tid * 16, z1 = z0 + 8192;
    int y0 = z0 ^ (((z0 >> 7) & 7) << 4);
    int y1 = z1 ^ (((z1 >> 7) & 7) << 4);
    int row0s = ((y0 >> 7) << 1) | ((y0 >> 6) & 1), kbe0 = (y0 & 63) >> 1;
    int row1s = ((y1 >> 7) << 1) | ((y1 >> 6) & 1), kbe1 = (y1 & 63) >> 1;
    const ushort* gA0 = &X[(size_t)(bm * 256 + row0s) * 2048 + kbe0];
    const ushort* gA1 = &X[(size_t)(bm * 256 + row1s) * 2048 + kbe1];
    const ushort* gB0 = &W[(size_t)(bn * 256 + row0s) * 2048 + kbe0];
    const ushort* gB1 = &W[(size_t)(bn * 256 + row1s) * 2048 + kbe1];
    int wOff = w * 1024;

#define STAGE(DB, ARR, KP, P0, P1, KO) do { \
    gload_lds16((P0) + (KO) + (KP) * 32, (char*)(ARR) + (DB) * 32768 + (KP) * 16384 + wOff); \
    gload_lds16((P1) + (KO) + (KP) * 32, (char*)(ARR) + (DB) * 32768 + (KP) * 16384 + wOff + 8192); \
} while (0)

    f32x4 acc[8][4] = {};
    bf16x8 bLo[4], bHi[4], aE[4], aO[4];
    STAGE(0, AL, 0, gA0, gA1, 0);
    STAGE(0, BL, 0, gB0, gB1, 0);
    STAGE(0, AL, 1, gA0, gA1, 0);
    STAGE(0, BL, 1, gB0, gB1, 0);
    asm volatile("s_waitcnt vmcnt(4)" ::: "memory");
    __builtin_amdgcn_s_barrier();
    __builtin_amdgcn_sched_barrier(0);
    {
        const char* Ab = (const char*)AL;
        const char* Bb = (const char*)BL;
        #pragma unroll
        for (int i = 0; i < 4; i++) {
            bLo[i] = RD8(Bb, bBase + i * 1024);
            aE[i]  = RD8(Ab, aBase + i * 1024);
        }
    }

    for (int t = 0; t < 32; ++t) {
        int buf = t & 1, nb = buf ^ 1;
        int ko = ((t + 1) & 31) * 64;
        const char* Ab  = (const char*)AL + buf * 32768;
        const char* Bb  = (const char*)BL + buf * 32768;
        const char* AbN = (const char*)AL + nb * 32768;
        const char* BbN = (const char*)BL + nb * 32768;
        // ---- phase A ----
        #pragma unroll
        for (int i = 0; i < 4; i++) aO[i] = RD8(Ab, aBase + 4096 + i * 1024);
        STAGE(nb, AL, 0, gA0, gA1, ko);
        __builtin_amdgcn_s_setprio(1);
        MMX(0, aE, bLo);
        __builtin_amdgcn_s_setprio(0);
        __builtin_amdgcn_sched_barrier(0);
        // ---- phase B ----
        asm volatile("s_waitcnt vmcnt(2)" ::: "memory");
        __builtin_amdgcn_s_barrier();
        __builtin_amdgcn_sched_barrier(0);
        #pragma unroll
        for (int i = 0; i < 4; i++) {
            bHi[i] = RD8(Bb, bBase + 16384 + i * 1024);
            aE[i]  = RD8(Ab, aBase + 16384 + i * 1024);
        }
        STAGE(nb, BL, 0, gB0, gB1, ko);
        __builtin_amdgcn_s_setprio(1);
        MMX(4, aO, bLo);
        __builtin_amdgcn_s_setprio(0);
        __builtin_amdgcn_sched_barrier(0);
        // ---- phase C ----
        #pragma unroll
        for (int i = 0; i < 4; i++) aO[i] = RD8(Ab, aBase + 16384 + 4096 + i * 1024);
        STAGE(nb, AL, 1, gA0, gA1, ko);
        __builtin_amdgcn_s_setprio(1);
        MMX(0, aE, bHi);
        __builtin_amdgcn_s_setprio(0);
        __builtin_amdgcn_sched_barrier(0);
        // ---- phase D ----
        asm volatile("s_waitcnt vmcnt(2)" ::: "memory");
        __builtin_amdgcn_s_barrier();
        __builtin_amdgcn_sched_barrier(0);
        #pragma unroll
        for (int i = 0; i < 4; i++) {
            bLo[i] = RD8(BbN, bBase + i * 1024);
            aE[i]  = RD8(AbN, aBase + i * 1024);
        }
        STAGE(nb, BL, 1, gB0, gB1, ko);
        __builtin_amdgcn_s_setprio(1);
        MMX(4, aO, bHi);
        __builtin_amdgcn_s_setprio(0);
        __builtin_amdgcn_sched_barrier(0);
    }
    asm volatile("s_waitcnt vmcnt(0)" ::: "memory");

    int rq = g * 4;
    #pragma unroll
    for (int mf = 0; mf < 8; mf++) {
        int row0 = bm * 256 + wr * 128 + mf * 16 + rq;
        #pragma unroll
        for (int n = 0; n < 4; n++) {
            int cb0 = bn * 256 + wc * 64 + n * 16;
            int col = cb0 + lr;
            if (cb0 < 4096) {
                #pragma unroll
                for (int r = 0; r < 4; r++)
                    zbuf[(size_t)(row0 + r) * DINNER + col] = f2bf(acc[mf][n][r]);
            } else if (cb0 < 10240) {
                #pragma unroll
                for (int r = 0; r < 4; r++)
                    xbc[(size_t)(row0 + r) * CONVDIM + (col - 4096)] = f2bf(acc[mf][n][r]);
            } else if (cb0 < 10304) {
                #pragma unroll
                for (int r = 0; r < 4; r++)
                    dtraw[(size_t)(row0 + r) * 64 + (col - 10240)] = acc[mf][n][r];
            }
        }
    }
}
#undef STAGE

// ============================================================
// out_proj: 256x128-tile pipelined GEMM with pre-read (round 13, verified)
// ============================================================
#define MM8(M0, AV, BV) do { \
  _Pragma("unroll") \
  for (int _m = 0; _m < 2; _m++) \
    _Pragma("unroll") \
    for (int _n = 0; _n < 4; _n++) \
      acc[(M0)+_m][_n] = MFMA_OP(AV[(M0)+_m], BV[_n], acc[(M0)+_m][_n], 0, 0, 0); \
} while (0)

__global__ __launch_bounds__(512, 2) void gemm256_out(
    const ushort* __restrict__ X, const ushort* __restrict__ W,
    float* __restrict__ outF) {
    __shared__ ushort AL[2][16384];
    __shared__ ushort BL[2][8192];
    int q = gridDim.x >> 3;
    int wg = blockIdx.x;
    int swz = (wg & 7) * q + (wg >> 3);
    int per = 16 * 4;
    int sg = swz / per, rr = swz % per;
    int bm = sg * 4 + (rr & 3);
    int bn = rr >> 2;
    int tid = threadIdx.x;
    int lane = tid & 63, w = tid >> 6;
    int wr = w >> 1, wc = w & 1;
    int lr = lane & 15, g = lane >> 4;
    int y00 = ((lr >> 1) << 7) | ((lr & 1) << 6) | (g << 4);
    int z00 = y00 ^ (((y00 >> 7) & 7) << 4);
    int aBase = wr * 4096 + z00;
    int bBase = wc * 4096 + z00;
    int z0 = tid * 16, z1 = z0 + 8192;
    int y0 = z0 ^ (((z0 >> 7) & 7) << 4);
    int y1 = z1 ^ (((z1 >> 7) & 7) << 4);
    int rowA0 = ((y0 >> 7) << 1) | ((y0 >> 6) & 1), kA0 = (y0 & 63) >> 1;
    int rowA1 = ((y1 >> 7) << 1) | ((y1 >> 6) & 1), kA1 = (y1 & 63) >> 1;
    const ushort* gA0 = &X[(size_t)(bm * 256 + rowA0) * 4096 + kA0];
    const ushort* gA1 = &X[(size_t)(bm * 256 + rowA1) * 4096 + kA1];
    const ushort* gB  = &W[(size_t)(bn * 128 + rowA0) * 4096 + kA0];
    int wOff = w * 1024;

#define STAGEA(DB, KP, KO) do { \
    gload_lds16(gA0 + (KO) + (KP) * 32, (char*)AL + (DB) * 32768 + (KP) * 16384 + wOff); \
    gload_lds16(gA1 + (KO) + (KP) * 32, (char*)AL + (DB) * 32768 + (KP) * 16384 + wOff + 8192); \
} while (0)
#define STAGEB(DB, KP, KO) \
    gload_lds16(gB + (KO) + (KP) * 32, (char*)BL + (DB) * 16384 + (KP) * 8192 + wOff)

    f32x4 acc[4][4] = {};
    bf16x8 aP[4], bP[4], aQ[4], bQ[4];
    STAGEA(0, 0, 0); STAGEB(0, 0, 0);
    STAGEA(0, 1, 0); STAGEB(0, 1, 0);
    asm volatile("s_waitcnt vmcnt(3)" ::: "memory");
    __builtin_amdgcn_s_barrier();
    __builtin_amdgcn_sched_barrier(0);
    #pragma unroll
    for (int i = 0; i < 4; i++) {
        bP[i] = RD8((const char*)BL, bBase + i * 1024);
        aP[i] = RD8((const char*)AL, aBase + i * 1024);
    }

    for (int t = 0; t < 64; ++t) {
        int buf = t & 1, nb = buf ^ 1;
        int ko = ((t + 1) & 63) * 64;
        const char* Ab  = (const char*)AL + buf * 32768;
        const char* Bb  = (const char*)BL + buf * 16384;
        const char* AbN = (const char*)AL + nb * 32768;
        const char* BbN = (const char*)BL + nb * 16384;
        STAGEA(nb, 0, ko); STAGEB(nb, 0, ko);
        __builtin_amdgcn_s_setprio(1);
        MM8(0, aP, bP);
        MM8(2, aP, bP);
        __builtin_amdgcn_s_setprio(0);
        __builtin_amdgcn_sched_barrier(0);
        asm volatile("s_waitcnt vmcnt(3)" ::: "memory");
        __builtin_amdgcn_s_barrier();
        __builtin_amdgcn_sched_barrier(0);
        #pragma unroll
        for (int i = 0; i < 4; i++) {
            bQ[i] = RD8(Bb, bBase + 8192 + i * 1024);
            aQ[i] = RD8(Ab, aBase + 16384 + i * 1024);
        }
        STAGEA(nb, 1, ko); STAGEB(nb, 1, ko);
        __builtin_amdgcn_s_setprio(1);
        MM8(0, aQ, bQ);
        __builtin_amdgcn_s_setprio(0);
        __builtin_amdgcn_sched_barrier(0);
        asm volatile("s_waitcnt vmcnt(3)" ::: "memory");
        __builtin_amdgcn_s_barrier();
        __builtin_amdgcn_sched_barrier(0);
        #pragma unroll
        for (int i = 0; i < 4; i++) {
            bP[i] = RD8(BbN, bBase + i * 1024);
            aP[i] = RD8(AbN, aBase + i * 1024);
        }
        __builtin_amdgcn_s_setprio(1);
        MM8(2, aQ, bQ);
        __builtin_amdgcn_s_setprio(0);
        __builtin_amdgcn_sched_barrier(0);
    }
    asm volatile("s_waitcnt vmcnt(0)" ::: "memory");

    int rq = g * 4;
    #pragma unroll
    for (int mf = 0; mf < 4; mf++) {
        int row0 = bm * 256 + wr * 64 + mf * 16 + rq;
        #pragma unroll
        for (int nf = 0; nf < 4; nf++) {
            int col = bn * 128 + wc * 64 + nf * 16 + lr;
            #pragma unroll
            for (int r = 0; r < 4; r++)
                outF[(size_t)(row0 + r) * DMODEL + col] = acc[mf][nf][r];
        }
    }
}
#undef STAGEA
#undef STAGEB

// ============================================================
// merged: causal conv1d (K=4, 8 rows x 8 ch per thread) + SiLU
//         || fused softplus+cumsum (independent data; block-range split)
// grid = 1536 (conv: 3 x 512 rows/8) + 1024 (cumsum) = 2560
// ============================================================
__global__ void conv_cumsum(const ushort* __restrict__ xbc, const float* __restrict__ cw,
                            const float* __restrict__ cb, ushort* __restrict__ convout,
                            float* __restrict__ dtbuf, const float* __restrict__ dt_bias,
                            const float* __restrict__ A_log, float* __restrict__ dAcs) {
    __shared__ float s[256];
    int bid = blockIdx.x;
    int tid = threadIdx.x;
    if (bid < 1536) {
        // ---- conv part ----
        int c8 = ((bid % 3) * 256 + tid) * 8;   // channel base
        int row0 = (bid / 3) * 8;               // token base (8 rows; 2048%8==0)
        int t0 = row0 & 2047;
        float bias[8];
        {
            float4 b0 = ((const float4*)cb)[c8 / 4];
            float4 b1 = ((const float4*)cb)[c8 / 4 + 1];
            bias[0] = b0.x; bias[1] = b0.y; bias[2] = b0.z; bias[3] = b0.w;
            bias[4] = b1.x; bias[5] = b1.y; bias[6] = b1.z; bias[7] = b1.w;
        }
        float wk[8][4];
        #pragma unroll
        for (int e = 0; e < 8; e++) {
            float4 wv = ((const float4*)cw)[c8 + e];
            wk[e][0] = wv.x; wk[e][1] = wv.y; wk[e][2] = wv.z; wk[e][3] = wv.w;
        }
        float f[11][8];
        #pragma unroll
        for (int j = 0; j < 11; j++) {
            int tt = t0 - 3 + j;
            if (tt >= 0) {
                uint4 v = *(const uint4*)&xbc[(size_t)(row0 - 3 + j) * CONVDIM + c8];
                unpack8(v, f[j]);
            } else {
                #pragma unroll
                for (int e = 0; e < 8; e++) f[j][e] = 0.f;
            }
        }
        #pragma unroll
        for (int r = 0; r < 8; r++) {
            float a[8];
            #pragma unroll
            for (int e = 0; e < 8; e++) {
                a[e] = bias[e];
                #pragma unroll
                for (int k = 0; k < 4; k++) a[e] += f[r + k][e] * wk[e][k];
            }
            uint4 o;
            float sv[8];
            #pragma unroll
            for (int e = 0; e < 8; e++) sv[e] = a[e] / (1.f + __expf(-a[e]));
            o.x = pk2(sv[0], sv[1]); o.y = pk2(sv[2], sv[3]);
            o.z = pk2(sv[4], sv[5]); o.w = pk2(sv[6], sv[7]);
            *(uint4*)&convout[(size_t)(row0 + r) * CONVDIM + c8] = o;
        }
    } else {
        // ---- cumsum part ----
        int bi = bid - 1536;                    // (cg)*64 + h
        int h = bi & 63, cg = bi >> 6;
        int t = tid;
        size_t didx = (size_t)(cg * 256 + t) * 64 + h;
        float x = dtbuf[didx] + dt_bias[h];
        float sp = (x > 20.f) ? x : log1pf(__expf(x));
        dtbuf[didx] = sp;
        float A = -expf(A_log[h]);
        float v = sp * A;
        s[t] = v;
        __syncthreads();
        for (int off = 1; off < 256; off <<= 1) {
            float add = (t >= off) ? s[t - off] : 0.f;
            __syncthreads();
            s[t] += add;
            __syncthreads();
        }
        dAcs[(size_t)bi * 256 + t] = s[t];
    }
}

// ============================================================
// MFMA states: per (cg,h), states[p][n] = sum_s xdt'[s,p] * B[s,n]
// ============================================================
__global__ __launch_bounds__(256) void states_mfma(
    const ushort* __restrict__ convout, const float* __restrict__ dtsp,
    const float* __restrict__ dAcs, float* __restrict__ states) {
    __shared__ ushort BT[128 * 72];
    __shared__ ushort XT[64 * 72];
    int bi = blockIdx.x;
    int h = bi & 63, cg = bi >> 6;
    int tid = threadIdx.x;
    int rowbase = cg * 256;
    int bcol = 1024 + ((h >> 3) << 7);
    int xcol = ((h >> 3) << 7) + ((h & 1) << 6);
    float dAlast = dAcs[(size_t)bi * 256 + 255];
    int w = tid >> 6, lane = tid & 63, g = lane >> 4, cc = lane & 15;
    f32x4 acc[4][2] = {};
    for (int T = 0; T < 4; T++) {
        __syncthreads();
        int s = lane;
        int srow = rowbase + T * 64 + s;
        #pragma unroll
        for (int i = 0; i < 4; i++) {
            int n0 = (w + i * 4) * 8;
            uint4 v = *(const uint4*)&convout[(size_t)srow * CONVDIM + bcol + n0];
            ushort us[8];
            us[0] = (ushort)v.x; us[1] = (ushort)(v.x >> 16);
            us[2] = (ushort)v.y; us[3] = (ushort)(v.y >> 16);
            us[4] = (ushort)v.z; us[5] = (ushort)(v.z >> 16);
            us[6] = (ushort)v.w; us[7] = (ushort)(v.w >> 16);
            #pragma unroll
            for (int e = 0; e < 8; e++) BT[(n0 + e) * 72 + s] = us[e];
        }
        float wgt = dtsp[(size_t)srow * 64 + h] * __expf(dAlast - dAcs[(size_t)bi * 256 + T * 64 + s]);
        #pragma unroll
        for (int j = 0; j < 2; j++) {
            int p0 = (w * 2 + j) * 8;
            uint4 v = *(const uint4*)&convout[(size_t)srow * CONVDIM + xcol + p0];
            float f[8]; unpack8(v, f);
            #pragma unroll
            for (int e = 0; e < 8; e++) XT[(p0 + e) * 72 + s] = f2bf(f[e] * wgt);
        }
        __syncthreads();
        bf16x8 af[4][2], bw[2][2];
        #pragma unroll
        for (int m = 0; m < 4; m++)
            #pragma unroll
            for (int kb = 0; kb < 2; kb++)
                af[m][kb] = *(const bf16x8*)&XT[(m * 16 + cc) * 72 + kb * 32 + 8 * g];
        #pragma unroll
        for (int np = 0; np < 2; np++)
            #pragma unroll
            for (int kb = 0; kb < 2; kb++)
                bw[np][kb] = *(const bf16x8*)&BT[(w * 32 + np * 16 + cc) * 72 + kb * 32 + 8 * g];
        #pragma unroll
        for (int m = 0; m < 4; m++)
            #pragma unroll
            for (int np = 0; np < 2; np++) {
                acc[m][np] = MFMA_OP(af[m][0], bw[np][0], acc[m][np], 0, 0, 0);
                acc[m][np] = MFMA_OP(af[m][1], bw[np][1], acc[m][np], 0, 0, 0);
            }
    }
    size_t base = (size_t)bi * 8192;
    #pragma unroll
    for (int m = 0; m < 4; m++)
        #pragma unroll
        for (int np = 0; np < 2; np++)
            #pragma unroll
            for (int r = 0; r < 4; r++) {
                int p = m * 16 + 4 * g + r;
                int n = w * 32 + np * 16 + cc;
                states[base + (size_t)p * 128 + n] = acc[m][np][r];
            }
}

// ============================================================
// inter-chunk recurrence: 8 chunks PER BATCH, carry resets per batch
// ============================================================
__global__ void recur_kernel(const float* __restrict__ dAcs, float* __restrict__ states) {
    int blk = blockIdx.x;
    int pq = blk & 7, bh = blk >> 3;
    int h = bh & 63, b = bh >> 6;
    int tid = threadIdx.x;
    int p = pq * 8 + (tid >> 5);
    int n0 = (tid & 31) * 4;
    float4 carry = make_float4(0.f, 0.f, 0.f, 0.f);
    for (int c = 0; c < 8; c++) {
        int bi = (b * 8 + c) * 64 + h;
        float decay = __expf(dAcs[(size_t)bi * 256 + 255]);
        size_t idx = (size_t)bi * 8192 + (size_t)p * 128 + n0;
        float4 tmp = *(const float4*)&states[idx];
        *(float4*)&states[idx] = carry;
        carry.x = carry.x * decay + tmp.x;
        carry.y = carry.y * decay + tmp.y;
        carry.z = carry.z * decay + tmp.z;
        carry.w = carry.w * decay + tmp.w;
    }
}

// ============================================================
// MFMA yscan (wave-balanced, round 15 — verified)
// ============================================================
__global__ __launch_bounds__(256, 2) void yscan_mfma(
    const ushort* __restrict__ convout, const float* __restrict__ dtsp,
    const float* __restrict__ dAcs, const float* __restrict__ states,
    ushort* __restrict__ y) {
    __shared__ ushort XT[64 * 264];
    __shared__ ushort PR[64 * 136];
    __shared__ ushort PV[4 * 16 * 72];
    __shared__ float sdA[256];
    int bi = blockIdx.x;
    int h = bi & 63, cg = bi >> 6;
    int tid = threadIdx.x;
    int rowbase = cg * 256;
    int bcol = 1024 + ((h >> 3) << 7);
    int ccol = 2048 + ((h >> 1) << 7);
    int xcol = ((h >> 3) << 7) + ((h & 1) << 6);

    sdA[tid] = dAcs[(size_t)bi * 256 + tid];
    #pragma unroll
    for (int i = 0; i < 4; i++) {
        int s = i * 64 + (tid & 63);
        float dtv = dtsp[(size_t)(rowbase + s) * 64 + h];
        #pragma unroll
        for (int j = 0; j < 2; j++) {
            int p0 = (((tid >> 6) << 1) + j) << 3;
            uint4 v = *(const uint4*)&convout[(size_t)(rowbase + s) * CONVDIM + xcol + p0];
            float f[8]; unpack8(v, f);
            #pragma unroll
            for (int e = 0; e < 8; e++) XT[(p0 + e) * 264 + s] = f2bf(f[e] * dtv);
        }
    }
    {
        const float* pv = &states[(size_t)bi * 8192];
        #pragma unroll
        for (int i = 0; i < 8; i++) {
            int flat = i * 1024 + tid * 4;
            float4 v = *(const float4*)&pv[flat];
            int p = flat >> 7, n = flat & 127;
            *(uint*)&PR[p * 136 + n]     = pk2(v.x, v.y);
            *(uint*)&PR[p * 136 + n + 2] = pk2(v.z, v.w);
        }
    }
    __syncthreads();

    int w = tid >> 6, lane = tid & 63, g = lane >> 4, c = lane & 15;
    const ushort* Crow0 = &convout[(size_t)(rowbase + w * 16 + c) * CONVDIM + ccol + 8 * g];

    // ---- Y_off = C . prev^T ----
    f32x4 yac[4][4] = {};
    #pragma unroll
    for (int kb = 0; kb < 4; kb++) {
        bf16x8 pb[4];
        #pragma unroll
        for (int np = 0; np < 4; np++)
            pb[np] = *(const bf16x8*)&PR[(16 * np + c) * 136 + kb * 32 + 8 * g];
        #pragma unroll
        for (int m = 0; m < 4; m++) {
            bf16x8 cf = *(const bf16x8*)&Crow0[(size_t)(m * 64) * CONVDIM + kb * 32];
            #pragma unroll
            for (int np = 0; np < 4; np++)
                yac[m][np] = MFMA_OP(cf, pb[np], yac[m][np], 0, 0, 0);
        }
    }
    float al[4][4];
    #pragma unroll
    for (int m = 0; m < 4; m++) {
        float Sm = sdA[m * 64];
        float eSm = __expf(Sm);
        #pragma unroll
        for (int r = 0; r < 4; r++) {
            float dAl = sdA[m * 64 + w * 16 + 4 * g + r];
            al[m][r] = __expf(dAl - Sm);
            float el = al[m][r] * eSm;
            #pragma unroll
            for (int np = 0; np < 4; np++) yac[m][np][r] *= el;
        }
    }

    // ---- s-tiles: T outer, m in [T,4) inner ----
    ushort* pvs = &PV[w * 1152];
    #pragma unroll
    for (int T = 0; T < 4; T++) {
        bf16x8 bbT[4][4];   // [kb][np]
        #pragma unroll
        for (int kb = 0; kb < 4; kb++)
            #pragma unroll
            for (int np = 0; np < 4; np++)
                bbT[kb][np] = *(const bf16x8*)&convout[(size_t)(rowbase + T * 64 + 16 * np + c) * CONVDIM + bcol + kb * 32 + 8 * g];
        bf16x8 xb[4][2];
        #pragma unroll
        for (int np = 0; np < 4; np++)
            #pragma unroll
            for (int k2 = 0; k2 < 2; k2++)
                xb[np][k2] = *(const bf16x8*)&XT[(16 * np + c) * 264 + T * 64 + k2 * 32 + 8 * g];
        float ET = sdA[T * 64 + 63];
        #pragma unroll
        for (int m = 0; m < 4; m++) {
            if (m < T) continue;
            f32x4 sac[4] = {};
            #pragma unroll
            for (int kb = 0; kb < 4; kb++) {
                bf16x8 cf = *(const bf16x8*)&Crow0[(size_t)(m * 64) * CONVDIM + kb * 32];
                #pragma unroll
                for (int np = 0; np < 4; np++)
                    sac[np] = MFMA_OP(cf, bbT[kb][np], sac[np], 0, 0, 0);
            }
            if (m > T) {
                float cTm = __expf(sdA[m * 64] - ET);
                #pragma unroll
                for (int np = 0; np < 4; np++) {
                    float bcv = __expf(ET - sdA[T * 64 + 16 * np + c]) * cTm;
                    #pragma unroll
                    for (int r = 0; r < 4; r++)
                        pvs[(4 * g + r) * 72 + 16 * np + c] = f2bf(sac[np][r] * (al[m][r] * bcv));
                }
            } else {
                float dal[4];
                #pragma unroll
                for (int r = 0; r < 4; r++) dal[r] = sdA[m * 64 + w * 16 + 4 * g + r];
                #pragma unroll
                for (int np = 0; np < 4; np++) {
                    int s_loc = m * 64 + 16 * np + c;
                    float dAs = sdA[s_loc];
                    #pragma unroll
                    for (int r = 0; r < 4; r++) {
                        int l_loc = m * 64 + w * 16 + 4 * g + r;
                        float v = (s_loc <= l_loc) ? sac[np][r] * __expf(dal[r] - dAs) : 0.f;
                        pvs[(4 * g + r) * 72 + 16 * np + c] = f2bf(v);
                    }
                }
            }
            bf16x8 pa0 = *(const bf16x8*)&pvs[c * 72 + 8 * g];
            bf16x8 pa1 = *(const bf16x8*)&pvs[c * 72 + 32 + 8 * g];
            #pragma unroll
            for (int np = 0; np < 4; np++) {
                yac[m][np] = MFMA_OP(pa0, xb[np][0], yac[m][np], 0, 0, 0);
                yac[m][np] = MFMA_OP(pa1, xb[np][1], yac[m][np], 0, 0, 0);
            }
        }
    }
    #pragma unroll
    for (int m = 0; m < 4; m++)
        #pragma unroll
        for (int np = 0; np < 4; np++)
            #pragma unroll
            for (int r = 0; r < 4; r++) {
                int l = m * 64 + w * 16 + 4 * g + r;
                y[(size_t)(rowbase + l) * DINNER + h * 64 + 16 * np + c] = f2bf(yac[m][np][r]);
            }
}

// ============================================================
// gated grouped RMSNorm: 8 ch/thread, uint4 loads, 16-thread groups
// grid (4096, 2): cbase = by*2048 + tid*8 (8 ch stay in one head-64 span)
// ============================================================
__global__ void norm_kernel(ushort* __restrict__ y, const ushort* __restrict__ zbuf,
                            const ushort* __restrict__ convout, const float* __restrict__ Dvec,
                            const float* __restrict__ nw) {
    int row = blockIdx.x;
    int cbase = blockIdx.y * 2048 + threadIdx.x * 8;
    int h = cbase >> 6;
    int p = cbase & 63;
    int xc = ((h >> 3) << 7) + ((h & 1) << 6) + p;
    uint4 yv = *(const uint4*)&y[(size_t)row * DINNER + cbase];
    uint4 zv = *(const uint4*)&zbuf[(size_t)row * DINNER + cbase];
    uint4 xv = *(const uint4*)&convout[(size_t)row * CONVDIM + xc];
    float fy[8], fz[8], fx[8];
    unpack8(yv, fy); unpack8(zv, fz); unpack8(xv, fx);
    float Dh = Dvec[h];
    float v[8];
    float ss = 0.f;
    #pragma unroll
    for (int e = 0; e < 8; e++) {
        float yy = fy[e] + Dh * fx[e];
        float vv = yy * (fz[e] / (1.f + __expf(-fz[e])));
        v[e] = vv;
        ss += vv * vv;
    }
    // reduce across the 16 threads covering this 128-ch group
    ss += __shfl_xor(ss, 1, 64);
    ss += __shfl_xor(ss, 2, 64);
    ss += __shfl_xor(ss, 4, 64);
    ss += __shfl_xor(ss, 8, 64);
    float rstd = rsqrtf(ss * (1.f / 128.f) + 1e-5f);
    float4 w0 = *(const float4*)&nw[cbase];
    float4 w1 = *(const float4*)&nw[cbase + 4];
    float wn[8] = {w0.x, w0.y, w0.z, w0.w, w1.x, w1.y, w1.z, w1.w};
    uint4 o;
    o.x = pk2(v[0] * rstd * wn[0], v[1] * rstd * wn[1]);
    o.y = pk2(v[2] * rstd * wn[2], v[3] * rstd * wn[3]);
    o.z = pk2(v[4] * rstd * wn[4], v[5] * rstd * wn[5]);
    o.w = pk2(v[6] * rstd * wn[6], v[7] * rstd * wn[7]);
    *(uint4*)&y[(size_t)row * DINNER + cbase] = o;
}

// ============================================================
extern "C" void kernel_launch(void* const* d_in, const int* in_sizes, int n_in,
                              void* d_out, int out_size, void* d_ws, size_t ws_size,
                              hipStream_t stream) {
    const float* u       = (const float*)d_in[0];
    const float* W_in    = (const float*)d_in[1];
    const float* conv_w  = (const float*)d_in[2];
    const float* conv_b  = (const float*)d_in[3];
    const float* dt_bias = (const float*)d_in[4];
    const float* A_log   = (const float*)d_in[5];
    const float* Dvec    = (const float*)d_in[6];
    const float* nw      = (const float*)d_in[7];
    const float* W_out   = (const float*)d_in[8];

    // ---- workspace layout (~196 MiB) ----
    char* ws = (char*)d_ws;
    size_t off = 0;
    auto alloc = [&](size_t bytes) { void* p = ws + off; off += (bytes + 255) & ~(size_t)255; return p; };
    ushort* zbuf    = (ushort*)alloc((size_t)LTOT * DINNER * 2);          // 32 MiB
    void*   shreg   = alloc((size_t)LTOT * CONVDIM * 2);                  // 48 MiB
    ushort* xbc     = (ushort*)shreg;
    float*  states  = (float*)shreg;
    float*  dtbuf   = (float*) alloc((size_t)LTOT * 64 * 4);              // 1 MiB
    void*   convreg = alloc((size_t)LTOT * CONVDIM * 2);                  // 48 MiB
    ushort* Win_bf  = (ushort*)convreg;
    ushort* convout = (ushort*)convreg;
    float*  dAcs    = (float*) alloc((size_t)1024 * 256 * 4);             // 1 MiB
    void*   ybreg   = alloc((size_t)LTOT * DINNER * 2);                   // 32 MiB
    ushort* u_bf    = (ushort*)ybreg;
    ushort* ybuf    = (ushort*)ybreg;
    ushort* Wout_bf = (ushort*)alloc((size_t)DMODEL * DINNER * 2);        // 17 MiB

    // fused bf16 conversions (one launch: u, W_in, W_out)
    cvt_all<<<dim3(36992), dim3(256), 0, stream>>>(u, W_in, W_out, u_bf, Win_bf, Wout_bf);
    // in_proj: round-13 proven pre-read kernel; grid 16 bm x 41 bn = 656
    gemm256_in<<<dim3(656), dim3(512), 0, stream>>>(u_bf, Win_bf, zbuf, xbc, dtbuf);
    // merged conv(8-row) + softplus/cumsum
    conv_cumsum<<<dim3(2560), dim3(256), 0, stream>>>(xbc, conv_w, conv_b, convout,
                                                      dtbuf, dt_bias, A_log, dAcs);
    // chunked scan
    states_mfma<<<dim3(1024), dim3(256), 0, stream>>>(convout, dtbuf, dAcs, states);
    recur_kernel<<<dim3(1024), dim3(256), 0, stream>>>(dAcs, states);
    yscan_mfma<<<dim3(1024), dim3(256), 0, stream>>>(convout, dtbuf, dAcs, states, ybuf);
    // gated group RMSNorm (8 ch/thread)
    norm_kernel<<<dim3(4096, 2), dim3(256), 0, stream>>>(ybuf, zbuf, convout, Dvec, nw);
    // out_proj: pre-read pipelined kernel; grid 256 (1/CU exact)
    gemm256_out<<<dim3(256), dim3(512), 0, stream>>>(ybuf, Wout_bf, (float*)d_out);
}